// Round 2
// baseline (310.044 us; speedup 1.0000x reference)
//
#include <hip/hip_runtime.h>
#include <stdint.h>

typedef unsigned short u16;
typedef __attribute__((ext_vector_type(8))) short short8;
typedef __attribute__((ext_vector_type(4))) float floatx4;

#define DEV static __device__ __forceinline__

struct alignas(8) us4 { u16 x, y, z, w; };
struct alignas(16) f4 { float x, y, z, w; };

DEV u16 f2bf(float f) {
  uint32_t u = __float_as_uint(f);
  u += 0x7fffu + ((u >> 16) & 1u);
  return (u16)(u >> 16);
}
DEV float bf2f(u16 h) { return __uint_as_float(((uint32_t)h) << 16); }

DEV void load_lds16(const void* g, void* l) {
  __builtin_amdgcn_global_load_lds((const __attribute__((address_space(1))) void*)g,
                                   (__attribute__((address_space(3))) void*)l, 16, 0, 0);
}

// ---------------- elementwise fp32 -> bf16 ----------------
__global__ void cvt_f32_bf16(const float* __restrict__ in, u16* __restrict__ out, int n) {
  int i = (blockIdx.x * blockDim.x + threadIdx.x) * 4;
  if (i < n) {
    f4 v = *(const f4*)(in + i);
    us4 o; o.x = f2bf(v.x); o.y = f2bf(v.y); o.z = f2bf(v.z); o.w = f2bf(v.w);
    *(us4*)(out + i) = o;
  }
}

// ---------------- transpose + convert: W[K][N] fp32 -> WT[N][K] bf16 ----------------
__global__ void transpose_cvt(const float* __restrict__ in, u16* __restrict__ out, int K, int N) {
  __shared__ float tile[32][33];
  const int n0 = blockIdx.x * 32, k0 = blockIdx.y * 32;
  const int tx = threadIdx.x, ty = threadIdx.y;
  for (int i = ty; i < 32; i += 8)
    tile[i][tx] = in[(size_t)(k0 + i) * N + n0 + tx];
  __syncthreads();
  for (int i = ty; i < 32; i += 8)
    out[(size_t)(n0 + i) * K + k0 + tx] = f2bf(tile[tx][i]);
}

// ---------------- bf16 GEMM, C = A[M,K] * Bt[N,K]^T + bias ----------------
// Tile: 128 x BN (BN = 128 or 64). EPI 0: scatter to qkv_pre. EPI 1: fp32 [M][N].
template <int EPI, int BN>
__global__ __launch_bounds__(256) void gemm_bt(const u16* __restrict__ A,
                                               const u16* __restrict__ Bt,
                                               const float* __restrict__ bias,
                                               void* __restrict__ outp,
                                               int M, int N, int K) {
  constexpr int NT = BN / 32;  // B-frags per wave
  __shared__ u16 lA[128 * 64];
  __shared__ u16 lB[BN * 64];
  const int t = threadIdx.x;
  const int w = t >> 6, lane = t & 63;
  const int quad = lane >> 4, l15 = lane & 15;
  const int wm = w >> 1, wn = w & 1;
  const int wn_off = wn * (BN / 2);
  const int m0 = blockIdx.y * 128, n0 = blockIdx.x * BN;

  floatx4 acc[4][NT] = {};

  const int srow = t >> 3;
  const int scol = (((t & 7) ^ (srow & 7)) << 3);  // XOR-swizzled source chunk
  const u16* gA = A + (size_t)(m0 + srow) * K + scol;
  const u16* gB = Bt + (size_t)(n0 + srow) * K + scol;
  u16* sA = lA + t * 8;
  u16* sB = lB + t * 8;
  const size_t rstep = (size_t)32 * K;

  for (int k0 = 0; k0 < K; k0 += 64) {
#pragma unroll
    for (int c = 0; c < 4; c++) load_lds16(gA + c * rstep, sA + c * 2048);
#pragma unroll
    for (int c = 0; c < BN / 32; c++) load_lds16(gB + c * rstep, sB + c * 2048);
    gA += 64; gB += 64;
    __syncthreads();
#pragma unroll
    for (int kc = 0; kc < 2; kc++) {
      short8 af[4], bfr[NT];
#pragma unroll
      for (int mt = 0; mt < 4; mt++)
        af[mt] = *(const short8*)&lA[(wm * 64 + mt * 16 + l15) * 64 + (((kc * 4 + quad) ^ (l15 & 7)) << 3)];
#pragma unroll
      for (int nt = 0; nt < NT; nt++)
        bfr[nt] = *(const short8*)&lB[(wn_off + nt * 16 + l15) * 64 + (((kc * 4 + quad) ^ (l15 & 7)) << 3)];
#pragma unroll
      for (int mt = 0; mt < 4; mt++)
#pragma unroll
        for (int nt = 0; nt < NT; nt++)
          acc[mt][nt] = __builtin_amdgcn_mfma_f32_16x16x32_bf16(af[mt], bfr[nt], acc[mt][nt], 0, 0, 0);
    }
    __syncthreads();
  }

  if (EPI == 0) {
    u16* outq = (u16*)outp;
#pragma unroll
    for (int nt = 0; nt < NT; nt++) {
      const int n = n0 + wn_off + nt * 16 + l15;
      const float bn = bias[n];
      const int tensor = n >> 10, e = n & 1023;
      const int h = e >> 6, d = e & 63;
      const size_t abase = (size_t)tensor * 4194304 + (size_t)h * 131072 + d;
#pragma unroll
      for (int mt = 0; mt < 4; mt++) {
        const int rb = m0 + wm * 64 + mt * 16 + quad * 4;
#pragma unroll
        for (int i = 0; i < 4; i++) {
          const int r = rb + i;
          const int b = r >> 11, s = r & 2047;
          outq[abase + (size_t)b * 2097152 + (size_t)s * 64] = f2bf(acc[mt][nt][i] + bn);
        }
      }
    }
  } else {
    float* outf = (float*)outp;
#pragma unroll
    for (int nt = 0; nt < NT; nt++) {
      const int n = n0 + wn_off + nt * 16 + l15;
      const float bn = bias[n];
#pragma unroll
      for (int mt = 0; mt < 4; mt++) {
        const int rb = m0 + wm * 64 + mt * 16 + quad * 4;
#pragma unroll
        for (int i = 0; i < 4; i++)
          outf[(size_t)(rb + i) * N + n] = acc[mt][nt][i] + bn;
      }
    }
  }
}

// ---------------- causal depthwise conv / head-mix ----------------
struct ConvW { const float* w[9]; const float* b[9]; };

__global__ __launch_bounds__(256) void conv_mix(const u16* __restrict__ qkv, ConvW cw,
                                                u16* __restrict__ qpost,
                                                u16* __restrict__ kpost,
                                                u16* __restrict__ vpostT) {
  __shared__ u16 xt[134 * 68];  // [s-halo 134][d 64 +4 pad]
  const int t = threadIdx.x;
  const int s0 = blockIdx.x * 128;
  const int h = blockIdx.y;
  const int tz = blockIdx.z;
  const int tensor = tz >> 1, b = tz & 1;
  const u16* src = qkv + (((size_t)tensor * 2 + b) * 16 + h) * 131072;

  for (int idx = t; idx < 134 * 16; idx += 256) {
    const int row = idx >> 4, c4 = (idx & 15) << 2;
    const int s = s0 - 6 + row;
    us4 v = {0, 0, 0, 0};
    if (s >= 0) v = *(const us4*)&src[(size_t)s * 64 + c4];
    *(us4*)&xt[row * 68 + c4] = v;
  }
  __syncthreads();

  const int group = h >> 2;
  const int ksz = group * 2 + 1;
  const float* wp = (group > 0) ? cw.w[tensor * 3 + group - 1] : nullptr;
  const float* bp = (group > 0) ? cw.b[tensor * 3 + group - 1] : nullptr;
  const float qscale = (tensor == 0) ? 0.125f : 1.0f;  // fold 1/sqrt(64) into Q

  if (tensor < 2) {
    u16* outp = (tensor == 0) ? qpost : kpost;
    const size_t ob = (((size_t)b * 16 + h) * 2048 + s0) * 64;
    for (int i = 0; i < 32; i++) {
      const int lin = t + i * 256;
      const int sl = lin >> 6, d = lin & 63;
      float val;
      if (group == 0) {
        val = bf2f(xt[(sl + 6) * 68 + d]);
      } else {
        val = bp[d];
        for (int jj = 0; jj < ksz; jj++)
          val += wp[d * ksz + jj] * bf2f(xt[(sl + 6 - (ksz - 1) + jj) * 68 + d]);
      }
      outp[ob + (size_t)sl * 64 + d] = f2bf(val * qscale);
    }
  } else {
    const size_t ob = ((size_t)b * 16 + h) * 64;
    for (int i = 0; i < 32; i++) {
      const int lin = t + i * 256;
      const int d = lin >> 7, sl = lin & 127;
      float val;
      if (group == 0) {
        val = bf2f(xt[(sl + 6) * 68 + d]);
      } else {
        val = bp[d];
        for (int jj = 0; jj < ksz; jj++)
          val += wp[d * ksz + jj] * bf2f(xt[(sl + 6 - (ksz - 1) + jj) * 68 + d]);
      }
      vpostT[(ob + d) * 2048 + s0 + sl] = f2bf(val);  // transposed [B,H,D,S]
    }
  }
}

// ---------------- causal flash attention (S^T formulation, dbuf pipeline) ----------------
// Q,K: [B,H,S,64] bf16 (Q pre-scaled by 1/8). V: [B,H,64,S] bf16. Out: [B,S,1024] bf16.
// q-tile 64 (16/wave), kv-tile 64, double-buffered K/V staging, 1 barrier/iter.
__global__ __launch_bounds__(256) void attn_fwd(const u16* __restrict__ Q,
                                                const u16* __restrict__ Kp,
                                                const u16* __restrict__ Vt,
                                                u16* __restrict__ Out) {
  __shared__ u16 lK[2][4096];   // [buf][kv 64][d 64]
  __shared__ u16 lV[2][4096];   // [buf][d 64][kv 64]
  __shared__ u16 lP[4][1024];   // per wave: [q_local 16][kv 64]
  const int t = threadIdx.x;
  const int w = t >> 6, lane = t & 63;
  const int quad = lane >> 4, l15 = lane & 15;
  const int e7 = l15 & 7;
  const int xb = blockIdx.x;
  const int qi = (xb & 1) ? (xb >> 1) : (31 - (xb >> 1));  // heavy/light interleave
  const int bh = blockIdx.y;
  const int b = bh >> 4, h = bh & 15;
  const size_t qkbase = (size_t)bh * 131072;
  const int qblk = qi * 64 + w * 16;

  // Q fragments (B-operand): lane holds Q[q=l15][d = kc*32 + quad*8 + j]
  short8 qf[2];
#pragma unroll
  for (int kc = 0; kc < 2; kc++)
    qf[kc] = *(const short8*)&Q[qkbase + (size_t)(qblk + l15) * 64 + kc * 32 + quad * 8];

  float mst = -3.0e38f;
  float lst = 0.0f;
  floatx4 accO[4] = {};

  // staging thread slots (XOR-swizzled source column so LDS[row][c] = G[row][c^(row&7)])
  const int srow = t >> 3;
  const int schunk = ((t & 7) ^ (srow & 7)) << 3;
  const u16* gK = Kp + qkbase + (size_t)srow * 64 + schunk;
  const u16* gV = Vt + qkbase + (size_t)srow * 2048 + schunk;
  u16* sK0 = &lK[0][0] + t * 8;
  u16* sV0 = &lV[0][0] + t * 8;
  u16* myP = lP[w];

  const int nj = qi + 1;

  // prologue: stage tile 0 into buf 0
  load_lds16(gK, sK0);
  load_lds16(gK + (size_t)32 * 64, sK0 + 2048);
  load_lds16(gV, sV0);
  load_lds16(gV + (size_t)32 * 2048, sV0 + 2048);

  for (int j = 0; j < nj; j++) {
    const int cur = j & 1;
    __syncthreads();  // loads for tile j complete; buf[cur] free of prior readers

    if (j + 1 < nj) {  // prefetch tile j+1 into the other buffer
      const int j0 = (j + 1) * 64;
      u16* sk = sK0 + (cur ^ 1) * 4096;
      u16* sv = sV0 + (cur ^ 1) * 4096;
      load_lds16(gK + (size_t)j0 * 64, sk);
      load_lds16(gK + (size_t)(j0 + 32) * 64, sk + 2048);
      load_lds16(gV + j0, sv);
      load_lds16(gV + (size_t)32 * 2048 + j0, sv + 2048);
    }

    const u16* cK = lK[cur];
    const u16* cV = lV[cur];
    const int j0 = j * 64;

    // S^T[kv][q] = K * Q^T
    floatx4 accS[4] = {};
#pragma unroll
    for (int kvt = 0; kvt < 4; kvt++)
#pragma unroll
      for (int kc = 0; kc < 2; kc++) {
        const short8 a = *(const short8*)&cK[(kvt * 16 + l15) * 64 + (((kc * 4 + quad) ^ e7) << 3)];
        accS[kvt] = __builtin_amdgcn_mfma_f32_16x16x32_bf16(a, qf[kc], accS[kvt], 0, 0, 0);
      }

    if (j == nj - 1) {  // causal mask on diagonal tile
      const int q = qblk + l15;
#pragma unroll
      for (int kvt = 0; kvt < 4; kvt++)
#pragma unroll
        for (int r = 0; r < 4; r++) {
          const int kv = j0 + kvt * 16 + quad * 4 + r;
          if (kv > q) accS[kvt][r] = -3.0e38f;
        }
    }

    // online softmax over kv for column q=l15 (partner lanes: +16,+32,+48)
    float tm = -3.0e38f;
#pragma unroll
    for (int kvt = 0; kvt < 4; kvt++)
#pragma unroll
      for (int r = 0; r < 4; r++)
        tm = fmaxf(tm, accS[kvt][r]);
    tm = fmaxf(tm, __shfl_xor(tm, 16));
    tm = fmaxf(tm, __shfl_xor(tm, 32));
    const float mnew = fmaxf(mst, tm);
    const float alpha = __expf(mst - mnew);
    mst = mnew;
    float ts = 0.0f;
#pragma unroll
    for (int kvt = 0; kvt < 4; kvt++) {
      const float p0 = __expf(accS[kvt][0] - mnew);
      const float p1 = __expf(accS[kvt][1] - mnew);
      const float p2 = __expf(accS[kvt][2] - mnew);
      const float p3 = __expf(accS[kvt][3] - mnew);
      ts += (p0 + p1) + (p2 + p3);
      us4 pk; pk.x = f2bf(p0); pk.y = f2bf(p1); pk.z = f2bf(p2); pk.w = f2bf(p3);
      const int slot = (kvt * 2 + (quad >> 1)) ^ e7;  // 16B-chunk XOR swizzle
      *(us4*)&myP[l15 * 64 + slot * 8 + (quad & 1) * 4] = pk;
    }
    ts += __shfl_xor(ts, 16);
    ts += __shfl_xor(ts, 32);
    lst = lst * alpha + ts;

#pragma unroll
    for (int dt = 0; dt < 4; dt++)
#pragma unroll
      for (int r = 0; r < 4; r++)
        accO[dt][r] *= alpha;

    asm volatile("s_waitcnt lgkmcnt(0)" ::: "memory");  // own-wave P writes visible

    // O^T[d][q] += V^T * P^T
#pragma unroll
    for (int kvc = 0; kvc < 2; kvc++) {
      const short8 pf = *(const short8*)&myP[l15 * 64 + (((kvc * 4 + quad) ^ e7) << 3)];
#pragma unroll
      for (int dt = 0; dt < 4; dt++) {
        const short8 vf = *(const short8*)&cV[(dt * 16 + l15) * 64 + (((kvc * 4 + quad) ^ e7) << 3)];
        accO[dt] = __builtin_amdgcn_mfma_f32_16x16x32_bf16(vf, pf, accO[dt], 0, 0, 0);
      }
    }
  }

  // epilogue: O[q=l15][d = dt*16+quad*4+r] = accO/l
  const float inv = 1.0f / lst;
  const size_t orow = ((size_t)b * 2048 + qblk + l15) * 1024 + h * 64;
#pragma unroll
  for (int dt = 0; dt < 4; dt++) {
    us4 o;
    o.x = f2bf(accO[dt][0] * inv);
    o.y = f2bf(accO[dt][1] * inv);
    o.z = f2bf(accO[dt][2] * inv);
    o.w = f2bf(accO[dt][3] * inv);
    *(us4*)&Out[orow + dt * 16 + quad * 4] = o;
  }
}

// ---------------- launcher ----------------
extern "C" void kernel_launch(void* const* d_in, const int* in_sizes, int n_in,
                              void* d_out, int out_size, void* d_ws, size_t ws_size,
                              hipStream_t stream) {
  (void)in_sizes; (void)n_in; (void)out_size; (void)ws_size;
  const float* hidden = (const float*)d_in[0];
  const float* attn_w = (const float*)d_in[1];
  const float* attn_b = (const float*)d_in[2];
  const float* proj_w = (const float*)d_in[3];
  const float* proj_b = (const float*)d_in[4];
  ConvW cw;
  for (int i = 0; i < 9; i++) {
    cw.w[i] = (const float*)d_in[5 + 2 * i];
    cw.b[i] = (const float*)d_in[6 + 2 * i];
  }

  uint8_t* ws = (uint8_t*)d_ws;
  u16* h_bf   = (u16*)(ws + 0);          //  8,388,608 B  hidden bf16 [4096][1024]
  u16* wqkvT  = (u16*)(ws + 8388608);    //  6,291,456 B  c_attn_w^T bf16 [3072][1024]
  u16* wprojT = (u16*)(ws + 14680064);   //  2,097,152 B  c_proj_w^T bf16 [1024][1024]
  u16* qkvpre = (u16*)(ws + 16777216);   // 25,165,824 B  [3][2][16][2048][64]
  u16* qpost  = (u16*)(ws + 41943040);   //  8,388,608 B  [2][16][2048][64]
  u16* kpost  = (u16*)(ws + 50331648);   //  8,388,608 B
  u16* vpostT = (u16*)(ws + 58720256);   //  8,388,608 B  [2][16][64][2048]
  u16* attno  = (u16*)(ws + 67108864);   //  8,388,608 B  [2][2048][1024]

  cvt_f32_bf16<<<4096, 256, 0, stream>>>(hidden, h_bf, 4194304);
  transpose_cvt<<<dim3(96, 32), dim3(32, 8), 0, stream>>>(attn_w, wqkvT, 1024, 3072);
  transpose_cvt<<<dim3(32, 32), dim3(32, 8), 0, stream>>>(proj_w, wprojT, 1024, 1024);
  gemm_bt<0, 128><<<dim3(24, 32), 256, 0, stream>>>(h_bf, wqkvT, attn_b, (void*)qkvpre, 4096, 3072, 1024);
  conv_mix<<<dim3(16, 16, 6), 256, 0, stream>>>(qkvpre, cw, qpost, kpost, vpostT);
  attn_fwd<<<dim3(32, 32), 256, 0, stream>>>(qpost, kpost, vpostT, attno);
  gemm_bt<1, 64><<<dim3(16, 32), 256, 0, stream>>>(attno, wprojT, proj_b, d_out, 4096, 1024, 1024);
}

// Round 4
// 303.655 us; speedup vs baseline: 1.0210x; 1.0210x over previous
//
#include <hip/hip_runtime.h>
#include <stdint.h>

typedef unsigned short u16;
typedef __attribute__((ext_vector_type(8))) short short8;
typedef __attribute__((ext_vector_type(4))) float floatx4;

#define DEV static __device__ __forceinline__

struct alignas(8) us4 { u16 x, y, z, w; };
struct alignas(16) f4 { float x, y, z, w; };

DEV u16 f2bf(float f) {
  uint32_t u = __float_as_uint(f);
  u += 0x7fffu + ((u >> 16) & 1u);
  return (u16)(u >> 16);
}
DEV float bf2f(u16 h) { return __uint_as_float(((uint32_t)h) << 16); }

DEV void load_lds16(const void* g, void* l) {
  __builtin_amdgcn_global_load_lds((const __attribute__((address_space(1))) void*)g,
                                   (__attribute__((address_space(3))) void*)l, 16, 0, 0);
}

// ---------------- elementwise fp32 -> bf16 ----------------
__global__ void cvt_f32_bf16(const float* __restrict__ in, u16* __restrict__ out, int n) {
  int i = (blockIdx.x * blockDim.x + threadIdx.x) * 4;
  if (i < n) {
    f4 v = *(const f4*)(in + i);
    us4 o; o.x = f2bf(v.x); o.y = f2bf(v.y); o.z = f2bf(v.z); o.w = f2bf(v.w);
    *(us4*)(out + i) = o;
  }
}

// ---------------- transpose + convert: W[K][N] fp32 -> WT[N][K] bf16 ----------------
__global__ void transpose_cvt(const float* __restrict__ in, u16* __restrict__ out, int K, int N) {
  __shared__ float tile[32][33];
  const int n0 = blockIdx.x * 32, k0 = blockIdx.y * 32;
  const int tx = threadIdx.x, ty = threadIdx.y;
  for (int i = ty; i < 32; i += 8)
    tile[i][tx] = in[(size_t)(k0 + i) * N + n0 + tx];
  __syncthreads();
  for (int i = ty; i < 32; i += 8)
    out[(size_t)(n0 + i) * K + k0 + tx] = f2bf(tile[tx][i]);
}

// ---------------- bf16 GEMM, C = A[M,K] * Bt[N,K]^T + bias ----------------
// MFMA operands SWAPPED so a lane holds (m = l15, n = quad*4+reg) -> 4 consecutive
// n per lane -> coalesced us4/f4 epilogue stores.
// EPI 0: qkv_pre [3][2][16][2048][64] bf16.  EPI 1: fp32 [M][N].
template <int EPI, int BN>
__global__ __launch_bounds__(256) void gemm_bt(const u16* __restrict__ A,
                                               const u16* __restrict__ Bt,
                                               const float* __restrict__ bias,
                                               void* __restrict__ outp,
                                               int M, int N, int K) {
  constexpr int NT = BN / 32;  // B-frags per wave
  __shared__ u16 lA[128 * 64];
  __shared__ u16 lB[BN * 64];
  const int t = threadIdx.x;
  const int w = t >> 6, lane = t & 63;
  const int quad = lane >> 4, l15 = lane & 15;
  const int wm = w >> 1, wn = w & 1;
  const int wn_off = wn * (BN / 2);
  const int m0 = blockIdx.y * 128, n0 = blockIdx.x * BN;

  floatx4 acc[4][NT] = {};

  const int srow = t >> 3;
  const int scol = (((t & 7) ^ (srow & 7)) << 3);  // XOR-swizzled source chunk
  const u16* gA = A + (size_t)(m0 + srow) * K + scol;
  const u16* gB = Bt + (size_t)(n0 + srow) * K + scol;
  u16* sA = lA + t * 8;
  u16* sB = lB + t * 8;
  const size_t rstep = (size_t)32 * K;

  for (int k0 = 0; k0 < K; k0 += 64) {
#pragma unroll
    for (int c = 0; c < 4; c++) load_lds16(gA + c * rstep, sA + c * 2048);
#pragma unroll
    for (int c = 0; c < BN / 32; c++) load_lds16(gB + c * rstep, sB + c * 2048);
    gA += 64; gB += 64;
    __syncthreads();
#pragma unroll
    for (int kc = 0; kc < 2; kc++) {
      short8 af[4], bfr[NT];
#pragma unroll
      for (int mt = 0; mt < 4; mt++)
        af[mt] = *(const short8*)&lA[(wm * 64 + mt * 16 + l15) * 64 + (((kc * 4 + quad) ^ (l15 & 7)) << 3)];
#pragma unroll
      for (int nt = 0; nt < NT; nt++)
        bfr[nt] = *(const short8*)&lB[(wn_off + nt * 16 + l15) * 64 + (((kc * 4 + quad) ^ (l15 & 7)) << 3)];
#pragma unroll
      for (int mt = 0; mt < 4; mt++)
#pragma unroll
        for (int nt = 0; nt < NT; nt++)
          acc[mt][nt] = __builtin_amdgcn_mfma_f32_16x16x32_bf16(bfr[nt], af[mt], acc[mt][nt], 0, 0, 0);
    }
    __syncthreads();
  }

  // epilogue: lane holds m = m0+wm*64+mt*16+l15 ; n = n0+wn_off+nt*16+quad*4+{0..3}
  if (EPI == 0) {
    u16* outq = (u16*)outp;
#pragma unroll
    for (int nt = 0; nt < NT; nt++) {
      const int nb = n0 + wn_off + nt * 16 + quad * 4;
      const f4 bn4 = *(const f4*)&bias[nb];
      const int tensor = nb >> 10, e = nb & 1023;
      const int h = e >> 6, d = e & 63;
      const size_t abase = (size_t)tensor * 4194304 + (size_t)h * 131072 + d;
#pragma unroll
      for (int mt = 0; mt < 4; mt++) {
        const int r = m0 + wm * 64 + mt * 16 + l15;
        const int b = r >> 11, s = r & 2047;
        us4 o;
        o.x = f2bf(acc[mt][nt][0] + bn4.x);
        o.y = f2bf(acc[mt][nt][1] + bn4.y);
        o.z = f2bf(acc[mt][nt][2] + bn4.z);
        o.w = f2bf(acc[mt][nt][3] + bn4.w);
        *(us4*)&outq[abase + (size_t)b * 2097152 + (size_t)s * 64] = o;
      }
    }
  } else {
    float* outf = (float*)outp;
#pragma unroll
    for (int nt = 0; nt < NT; nt++) {
      const int nb = n0 + wn_off + nt * 16 + quad * 4;
      const f4 bn4 = *(const f4*)&bias[nb];
#pragma unroll
      for (int mt = 0; mt < 4; mt++) {
        const int r = m0 + wm * 64 + mt * 16 + l15;
        f4 o;
        o.x = acc[mt][nt][0] + bn4.x;
        o.y = acc[mt][nt][1] + bn4.y;
        o.z = acc[mt][nt][2] + bn4.z;
        o.w = acc[mt][nt][3] + bn4.w;
        *(f4*)&outf[(size_t)r * N + nb] = o;
      }
    }
  }
}

// ---------------- causal depthwise conv / head-mix ----------------
struct ConvW { const float* w[9]; const float* b[9]; };

__global__ __launch_bounds__(256) void conv_mix(const u16* __restrict__ qkv, ConvW cw,
                                                u16* __restrict__ qpost,
                                                u16* __restrict__ kpost,
                                                u16* __restrict__ vpostT) {
  __shared__ u16 xt[134 * 68];  // [s-halo 134][d 64 +4 pad]
  const int t = threadIdx.x;
  const int s0 = blockIdx.x * 128;
  const int h = blockIdx.y;
  const int tz = blockIdx.z;
  const int tensor = tz >> 1, b = tz & 1;
  const u16* src = qkv + (((size_t)tensor * 2 + b) * 16 + h) * 131072;

  for (int idx = t; idx < 134 * 16; idx += 256) {
    const int row = idx >> 4, c4 = (idx & 15) << 2;
    const int s = s0 - 6 + row;
    us4 v = {0, 0, 0, 0};
    if (s >= 0) v = *(const us4*)&src[(size_t)s * 64 + c4];
    *(us4*)&xt[row * 68 + c4] = v;
  }
  __syncthreads();

  const int group = h >> 2;
  const int ksz = group * 2 + 1;
  const float* wp = (group > 0) ? cw.w[tensor * 3 + group - 1] : nullptr;
  const float* bp = (group > 0) ? cw.b[tensor * 3 + group - 1] : nullptr;
  const float qscale = (tensor == 0) ? 0.125f : 1.0f;  // fold 1/sqrt(64) into Q

  if (tensor < 2) {
    u16* outp = (tensor == 0) ? qpost : kpost;
    const size_t ob = (((size_t)b * 16 + h) * 2048 + s0) * 64;
    for (int i = 0; i < 32; i++) {
      const int lin = t + i * 256;
      const int sl = lin >> 6, d = lin & 63;
      float val;
      if (group == 0) {
        val = bf2f(xt[(sl + 6) * 68 + d]);
      } else {
        val = bp[d];
        for (int jj = 0; jj < ksz; jj++)
          val += wp[d * ksz + jj] * bf2f(xt[(sl + 6 - (ksz - 1) + jj) * 68 + d]);
      }
      outp[ob + (size_t)sl * 64 + d] = f2bf(val * qscale);
    }
  } else {
    const size_t ob = ((size_t)b * 16 + h) * 64;
    for (int i = 0; i < 32; i++) {
      const int lin = t + i * 256;
      const int d = lin >> 7, sl = lin & 127;
      float val;
      if (group == 0) {
        val = bf2f(xt[(sl + 6) * 68 + d]);
      } else {
        val = bp[d];
        for (int jj = 0; jj < ksz; jj++)
          val += wp[d * ksz + jj] * bf2f(xt[(sl + 6 - (ksz - 1) + jj) * 68 + d]);
      }
      vpostT[(ob + d) * 2048 + s0 + sl] = f2bf(val);  // transposed [B,H,D,S]
    }
  }
}

// ---------------- causal flash attention (S^T formulation) ----------------
// R1-proven kernel (replay-validated). Q,K: [B,H,S,64] bf16 (Q pre-scaled by 1/8).
// V: [B,H,64,S] bf16. Out: [B,S,1024] bf16.
__global__ __launch_bounds__(256) void attn_fwd(const u16* __restrict__ Q,
                                                const u16* __restrict__ Kp,
                                                const u16* __restrict__ Vt,
                                                u16* __restrict__ Out) {
  __shared__ u16 lK[128 * 64];       // [kv][d]
  __shared__ u16 lV[64 * 128];       // [d][kv]
  __shared__ u16 lP[4][32 * 128];    // per wave: [q_local][kv]
  const int t = threadIdx.x;
  const int w = t >> 6, lane = t & 63;
  const int quad = lane >> 4, l15 = lane & 15;
  const int xb = blockIdx.x;
  const int qi = (xb & 1) ? (xb >> 1) : (15 - (xb >> 1));  // interleave heavy/light blocks
  const int bh = blockIdx.y;
  const int b = bh >> 4, h = bh & 15;
  const size_t qkbase = (size_t)bh * 131072;
  const int qblk = qi * 128 + w * 32;

  // Q fragments (B-operand): lane holds Q[q = l15 + 16*qt][d = kc*32 + quad*8 + j]
  short8 qf[2][2];
#pragma unroll
  for (int qt = 0; qt < 2; qt++)
#pragma unroll
    for (int kc = 0; kc < 2; kc++)
      qf[qt][kc] = *(const short8*)&Q[qkbase + (size_t)(qblk + qt * 16 + l15) * 64 + kc * 32 + quad * 8];

  float mst[2] = {-3.0e38f, -3.0e38f};
  float lst[2] = {0.0f, 0.0f};
  floatx4 accO[4][2] = {};

  const int krow = t >> 3;
  const int kcol = (((t & 7) ^ (krow & 7)) << 3);
  const u16* gK = Kp + qkbase + (size_t)krow * 64 + kcol;
  const int vrow = t >> 4;
  const int vcol = (((t & 15) ^ vrow) << 3);
  const u16* gV = Vt + qkbase + (size_t)vrow * 2048 + vcol;
  u16* sK = lK + t * 8;
  u16* sV = lV + t * 8;
  u16* myP = lP[w];

  for (int j = 0; j <= qi; j++) {
    const int j0 = j * 128;
#pragma unroll
    for (int c = 0; c < 4; c++) {
      load_lds16(gK + (size_t)(j0 + c * 32) * 64, sK + c * 2048);
      load_lds16(gV + j0 + c * 16 * 2048, sV + c * 2048);
    }
    __syncthreads();

    // S^T[kv][q] = K * Q^T
    floatx4 accS[8][2] = {};
#pragma unroll
    for (int kvt = 0; kvt < 8; kvt++) {
#pragma unroll
      for (int kc = 0; kc < 2; kc++) {
        const short8 a = *(const short8*)&lK[(kvt * 16 + l15) * 64 + (((kc * 4 + quad) ^ (l15 & 7)) << 3)];
#pragma unroll
        for (int qt = 0; qt < 2; qt++)
          accS[kvt][qt] = __builtin_amdgcn_mfma_f32_16x16x32_bf16(a, qf[qt][kc], accS[kvt][qt], 0, 0, 0);
      }
    }

    if (j == qi) {  // causal mask on diagonal tile
#pragma unroll
      for (int qt = 0; qt < 2; qt++) {
        const int q = qblk + qt * 16 + l15;
#pragma unroll
        for (int kvt = 0; kvt < 8; kvt++)
#pragma unroll
          for (int r = 0; r < 4; r++) {
            const int kv = j0 + kvt * 16 + quad * 4 + r;
            if (kv > q) accS[kvt][qt][r] = -3.0e38f;
          }
      }
    }

    float alpha[2];
#pragma unroll
    for (int qt = 0; qt < 2; qt++) {
      float tm = -3.0e38f;
#pragma unroll
      for (int kvt = 0; kvt < 8; kvt++)
#pragma unroll
        for (int r = 0; r < 4; r++)
          tm = fmaxf(tm, accS[kvt][qt][r]);
      tm = fmaxf(tm, __shfl_xor(tm, 16));
      tm = fmaxf(tm, __shfl_xor(tm, 32));
      const float mnew = fmaxf(mst[qt], tm);
      alpha[qt] = __expf(mst[qt] - mnew);
      mst[qt] = mnew;
      float ts = 0.0f;
      const int prow = (qt * 16 + l15) * 128;
#pragma unroll
      for (int kvt = 0; kvt < 8; kvt++) {
        const float p0 = __expf(accS[kvt][qt][0] - mnew);
        const float p1 = __expf(accS[kvt][qt][1] - mnew);
        const float p2 = __expf(accS[kvt][qt][2] - mnew);
        const float p3 = __expf(accS[kvt][qt][3] - mnew);
        ts += (p0 + p1) + (p2 + p3);
        us4 pk; pk.x = f2bf(p0); pk.y = f2bf(p1); pk.z = f2bf(p2); pk.w = f2bf(p3);
        const int slot = (kvt * 2 + (quad >> 1)) ^ (l15 & 7);  // 16B-chunk XOR swizzle
        *(us4*)&myP[prow + slot * 8 + (quad & 1) * 4] = pk;
      }
      ts += __shfl_xor(ts, 16);
      ts += __shfl_xor(ts, 32);
      lst[qt] = lst[qt] * alpha[qt] + ts;
    }

#pragma unroll
    for (int dt = 0; dt < 4; dt++)
#pragma unroll
      for (int qt = 0; qt < 2; qt++)
#pragma unroll
        for (int r = 0; r < 4; r++)
          accO[dt][qt][r] *= alpha[qt];

    asm volatile("s_waitcnt lgkmcnt(0)" ::: "memory");  // P writes visible to own wave

    // O^T[d][q] += V^T * P^T
#pragma unroll
    for (int kvc = 0; kvc < 4; kvc++) {
      short8 pf[2];
#pragma unroll
      for (int qt = 0; qt < 2; qt++)
        pf[qt] = *(const short8*)&myP[(qt * 16 + l15) * 128 + (((kvc * 4 + quad) ^ (l15 & 7)) << 3)];
#pragma unroll
      for (int dt = 0; dt < 4; dt++) {
        const short8 vf = *(const short8*)&lV[(dt * 16 + l15) * 128 + (((kvc * 4 + quad) ^ l15) << 3)];
#pragma unroll
        for (int qt = 0; qt < 2; qt++)
          accO[dt][qt] = __builtin_amdgcn_mfma_f32_16x16x32_bf16(vf, pf[qt], accO[dt][qt], 0, 0, 0);
      }
    }
    __syncthreads();
  }

  // epilogue: O[q][d] = O^T / l, write bf16 [B,S,E]
#pragma unroll
  for (int qt = 0; qt < 2; qt++) {
    const float inv = 1.0f / lst[qt];
    const int q = qblk + qt * 16 + l15;
#pragma unroll
    for (int dt = 0; dt < 4; dt++) {
      us4 o;
      o.x = f2bf(accO[dt][qt][0] * inv);
      o.y = f2bf(accO[dt][qt][1] * inv);
      o.z = f2bf(accO[dt][qt][2] * inv);
      o.w = f2bf(accO[dt][qt][3] * inv);
      *(us4*)&Out[((size_t)b * 2048 + q) * 1024 + h * 64 + dt * 16 + quad * 4] = o;
    }
  }
}

// ---------------- launcher ----------------
extern "C" void kernel_launch(void* const* d_in, const int* in_sizes, int n_in,
                              void* d_out, int out_size, void* d_ws, size_t ws_size,
                              hipStream_t stream) {
  (void)in_sizes; (void)n_in; (void)out_size; (void)ws_size;
  const float* hidden = (const float*)d_in[0];
  const float* attn_w = (const float*)d_in[1];
  const float* attn_b = (const float*)d_in[2];
  const float* proj_w = (const float*)d_in[3];
  const float* proj_b = (const float*)d_in[4];
  ConvW cw;
  for (int i = 0; i < 9; i++) {
    cw.w[i] = (const float*)d_in[5 + 2 * i];
    cw.b[i] = (const float*)d_in[6 + 2 * i];
  }

  uint8_t* ws = (uint8_t*)d_ws;
  u16* h_bf   = (u16*)(ws + 0);          //  8,388,608 B  hidden bf16 [4096][1024]
  u16* wqkvT  = (u16*)(ws + 8388608);    //  6,291,456 B  c_attn_w^T bf16 [3072][1024]
  u16* wprojT = (u16*)(ws + 14680064);   //  2,097,152 B  c_proj_w^T bf16 [1024][1024]
  u16* qkvpre = (u16*)(ws + 16777216);   // 25,165,824 B  [3][2][16][2048][64]
  u16* qpost  = (u16*)(ws + 41943040);   //  8,388,608 B  [2][16][2048][64]
  u16* kpost  = (u16*)(ws + 50331648);   //  8,388,608 B
  u16* vpostT = (u16*)(ws + 58720256);   //  8,388,608 B  [2][16][64][2048]
  u16* attno  = (u16*)(ws + 67108864);   //  8,388,608 B  [2][2048][1024]

  cvt_f32_bf16<<<4096, 256, 0, stream>>>(hidden, h_bf, 4194304);
  transpose_cvt<<<dim3(96, 32), dim3(32, 8), 0, stream>>>(attn_w, wqkvT, 1024, 3072);
  transpose_cvt<<<dim3(32, 32), dim3(32, 8), 0, stream>>>(proj_w, wprojT, 1024, 1024);
  gemm_bt<0, 128><<<dim3(24, 32), 256, 0, stream>>>(h_bf, wqkvT, attn_b, (void*)qkvpre, 4096, 3072, 1024);
  conv_mix<<<dim3(16, 16, 6), 256, 0, stream>>>(qkvpre, cw, qpost, kpost, vpostT);
  attn_fwd<<<dim3(16, 32), 256, 0, stream>>>(qpost, kpost, vpostT, attno);
  gemm_bt<1, 64><<<dim3(16, 32), 256, 0, stream>>>(attno, wprojT, proj_b, d_out, 4096, 1024, 1024);
}

// Round 5
// 300.512 us; speedup vs baseline: 1.0317x; 1.0105x over previous
//
#include <hip/hip_runtime.h>
#include <stdint.h>
#include <math.h>

typedef unsigned short u16;
typedef __attribute__((ext_vector_type(8))) short short8;
typedef __attribute__((ext_vector_type(4))) float floatx4;

#define DEV static __device__ __forceinline__

struct alignas(8) us4 { u16 x, y, z, w; };
struct alignas(16) f4 { float x, y, z, w; };
struct alignas(8) f2 { float x, y; };

DEV u16 f2bf(float f) {
  uint32_t u = __float_as_uint(f);
  u += 0x7fffu + ((u >> 16) & 1u);
  return (u16)(u >> 16);
}
DEV float bf2f(u16 h) { return __uint_as_float(((uint32_t)h) << 16); }

DEV void load_lds16(const void* g, void* l) {
  __builtin_amdgcn_global_load_lds((const __attribute__((address_space(1))) void*)g,
                                   (__attribute__((address_space(3))) void*)l, 16, 0, 0);
}

// ---------------- elementwise fp32 -> bf16 ----------------
__global__ void cvt_f32_bf16(const float* __restrict__ in, u16* __restrict__ out, int n) {
  int i = (blockIdx.x * blockDim.x + threadIdx.x) * 4;
  if (i < n) {
    f4 v = *(const f4*)(in + i);
    us4 o; o.x = f2bf(v.x); o.y = f2bf(v.y); o.z = f2bf(v.z); o.w = f2bf(v.w);
    *(us4*)(out + i) = o;
  }
}

// ---------------- transpose + convert: W[K][N] fp32 -> WT[N][K] bf16 ----------------
__global__ void transpose_cvt(const float* __restrict__ in, u16* __restrict__ out, int K, int N) {
  __shared__ float tile[32][33];
  const int n0 = blockIdx.x * 32, k0 = blockIdx.y * 32;
  const int tx = threadIdx.x, ty = threadIdx.y;
  for (int i = ty; i < 32; i += 8)
    tile[i][tx] = in[(size_t)(k0 + i) * N + n0 + tx];
  __syncthreads();
  for (int i = ty; i < 32; i += 8)
    out[(size_t)(n0 + i) * K + k0 + tx] = f2bf(tile[tx][i]);
}

// ---------------- bf16 GEMM, C = A[M,K] * Bt[N,K]^T + bias ----------------
// Operands swapped: lane holds (m = l15, n = quad*4+reg) -> coalesced us4/f4 stores.
template <int EPI, int BN>
__global__ __launch_bounds__(256) void gemm_bt(const u16* __restrict__ A,
                                               const u16* __restrict__ Bt,
                                               const float* __restrict__ bias,
                                               void* __restrict__ outp,
                                               int M, int N, int K) {
  constexpr int NT = BN / 32;
  __shared__ u16 lA[128 * 64];
  __shared__ u16 lB[BN * 64];
  const int t = threadIdx.x;
  const int w = t >> 6, lane = t & 63;
  const int quad = lane >> 4, l15 = lane & 15;
  const int wm = w >> 1, wn = w & 1;
  const int wn_off = wn * (BN / 2);
  const int m0 = blockIdx.y * 128, n0 = blockIdx.x * BN;

  floatx4 acc[4][NT] = {};

  const int srow = t >> 3;
  const int scol = (((t & 7) ^ (srow & 7)) << 3);
  const u16* gA = A + (size_t)(m0 + srow) * K + scol;
  const u16* gB = Bt + (size_t)(n0 + srow) * K + scol;
  u16* sA = lA + t * 8;
  u16* sB = lB + t * 8;
  const size_t rstep = (size_t)32 * K;

  for (int k0 = 0; k0 < K; k0 += 64) {
#pragma unroll
    for (int c = 0; c < 4; c++) load_lds16(gA + c * rstep, sA + c * 2048);
#pragma unroll
    for (int c = 0; c < BN / 32; c++) load_lds16(gB + c * rstep, sB + c * 2048);
    gA += 64; gB += 64;
    __syncthreads();
#pragma unroll
    for (int kc = 0; kc < 2; kc++) {
      short8 af[4], bfr[NT];
#pragma unroll
      for (int mt = 0; mt < 4; mt++)
        af[mt] = *(const short8*)&lA[(wm * 64 + mt * 16 + l15) * 64 + (((kc * 4 + quad) ^ (l15 & 7)) << 3)];
#pragma unroll
      for (int nt = 0; nt < NT; nt++)
        bfr[nt] = *(const short8*)&lB[(wn_off + nt * 16 + l15) * 64 + (((kc * 4 + quad) ^ (l15 & 7)) << 3)];
#pragma unroll
      for (int mt = 0; mt < 4; mt++)
#pragma unroll
        for (int nt = 0; nt < NT; nt++)
          acc[mt][nt] = __builtin_amdgcn_mfma_f32_16x16x32_bf16(bfr[nt], af[mt], acc[mt][nt], 0, 0, 0);
    }
    __syncthreads();
  }

  if (EPI == 0) {
    u16* outq = (u16*)outp;
#pragma unroll
    for (int nt = 0; nt < NT; nt++) {
      const int nb = n0 + wn_off + nt * 16 + quad * 4;
      const f4 bn4 = *(const f4*)&bias[nb];
      const int tensor = nb >> 10, e = nb & 1023;
      const int h = e >> 6, d = e & 63;
      const size_t abase = (size_t)tensor * 4194304 + (size_t)h * 131072 + d;
#pragma unroll
      for (int mt = 0; mt < 4; mt++) {
        const int r = m0 + wm * 64 + mt * 16 + l15;
        const int b = r >> 11, s = r & 2047;
        us4 o;
        o.x = f2bf(acc[mt][nt][0] + bn4.x);
        o.y = f2bf(acc[mt][nt][1] + bn4.y);
        o.z = f2bf(acc[mt][nt][2] + bn4.z);
        o.w = f2bf(acc[mt][nt][3] + bn4.w);
        *(us4*)&outq[abase + (size_t)b * 2097152 + (size_t)s * 64] = o;
      }
    }
  } else {
    float* outf = (float*)outp;
#pragma unroll
    for (int nt = 0; nt < NT; nt++) {
      const int nb = n0 + wn_off + nt * 16 + quad * 4;
      const f4 bn4 = *(const f4*)&bias[nb];
#pragma unroll
      for (int mt = 0; mt < 4; mt++) {
        const int r = m0 + wm * 64 + mt * 16 + l15;
        f4 o;
        o.x = acc[mt][nt][0] + bn4.x;
        o.y = acc[mt][nt][1] + bn4.y;
        o.z = acc[mt][nt][2] + bn4.z;
        o.w = acc[mt][nt][3] + bn4.w;
        *(f4*)&outf[(size_t)r * N + nb] = o;
      }
    }
  }
}

// ---------------- causal depthwise conv / head-mix ----------------
struct ConvW { const float* w[9]; const float* b[9]; };

__global__ __launch_bounds__(256) void conv_mix(const u16* __restrict__ qkv, ConvW cw,
                                                u16* __restrict__ qpost,
                                                u16* __restrict__ kpost,
                                                u16* __restrict__ vpostT) {
  __shared__ u16 xt[134 * 68];
  const int t = threadIdx.x;
  const int s0 = blockIdx.x * 128;
  const int h = blockIdx.y;
  const int tz = blockIdx.z;
  const int tensor = tz >> 1, b = tz & 1;
  const u16* src = qkv + (((size_t)tensor * 2 + b) * 16 + h) * 131072;

  for (int idx = t; idx < 134 * 16; idx += 256) {
    const int row = idx >> 4, c4 = (idx & 15) << 2;
    const int s = s0 - 6 + row;
    us4 v = {0, 0, 0, 0};
    if (s >= 0) v = *(const us4*)&src[(size_t)s * 64 + c4];
    *(us4*)&xt[row * 68 + c4] = v;
  }
  __syncthreads();

  const int group = h >> 2;
  const int ksz = group * 2 + 1;
  const float* wp = (group > 0) ? cw.w[tensor * 3 + group - 1] : nullptr;
  const float* bp = (group > 0) ? cw.b[tensor * 3 + group - 1] : nullptr;
  const float qscale = (tensor == 0) ? 0.125f : 1.0f;

  if (tensor < 2) {
    u16* outp = (tensor == 0) ? qpost : kpost;
    const size_t ob = (((size_t)b * 16 + h) * 2048 + s0) * 64;
    for (int i = 0; i < 32; i++) {
      const int lin = t + i * 256;
      const int sl = lin >> 6, d = lin & 63;
      float val;
      if (group == 0) {
        val = bf2f(xt[(sl + 6) * 68 + d]);
      } else {
        val = bp[d];
        for (int jj = 0; jj < ksz; jj++)
          val += wp[d * ksz + jj] * bf2f(xt[(sl + 6 - (ksz - 1) + jj) * 68 + d]);
      }
      outp[ob + (size_t)sl * 64 + d] = f2bf(val * qscale);
    }
  } else {
    const size_t ob = ((size_t)b * 16 + h) * 64;
    for (int i = 0; i < 32; i++) {
      const int lin = t + i * 256;
      const int d = lin >> 7, sl = lin & 127;
      float val;
      if (group == 0) {
        val = bf2f(xt[(sl + 6) * 68 + d]);
      } else {
        val = bp[d];
        for (int jj = 0; jj < ksz; jj++)
          val += wp[d * ksz + jj] * bf2f(xt[(sl + 6 - (ksz - 1) + jj) * 68 + d]);
      }
      vpostT[(ob + d) * 2048 + s0 + sl] = f2bf(val);
    }
  }
}

// ---------------- split-kv causal flash attention ----------------
// Uniform work decomposition: per (b,h), 72 slabs = sum over qi of ceil((qi+1)/2);
// each block = one (bh, qi, slab): 1-2 kv-tiles of 128. Inner body identical to the
// R1/R4-proven kernel. Multi-slab tiles write unnormalized O' (bf16) + (m,l); the
// reduce kernel combines. Single-slab (qi<=1) writes normalized output directly.
__global__ __launch_bounds__(256) void attn_fwd(const u16* __restrict__ Q,
                                                const u16* __restrict__ Kp,
                                                const u16* __restrict__ Vt,
                                                u16* __restrict__ Out,
                                                u16* __restrict__ Opart,
                                                f2* __restrict__ ml) {
  __shared__ u16 lK[128 * 64];       // [kv][d]
  __shared__ u16 lV[64 * 128];       // [d][kv]
  __shared__ u16 lP[4][32 * 128];    // per wave: [q_local][kv]
  const int t = threadIdx.x;
  const int w = t >> 6, lane = t & 63;
  const int quad = lane >> 4, l15 = lane & 15;

  // block -> (bh, qi, slab): pin each bh's 72 slabs to one XCD (%8 heuristic)
  const int lin = blockIdx.x;
  const int xcd = lin & 7;
  const int idx = lin >> 3;          // 0..287
  const int grp = idx / 72;          // 0..3
  const int u = idx - grp * 72;      // 0..71
  const int bh = grp * 8 + xcd;
  int p = (int)(0.5f * (sqrtf(4.0f * (float)u + 1.0f) - 1.0f));
  if ((p + 1) * (p + 2) <= u) p++;
  if (p * (p + 1) > u) p--;
  const int v = u - p * (p + 1);
  const int qi = 2 * p + (v >= p + 1 ? 1 : 0);
  const int slab = v - (v >= p + 1 ? p + 1 : 0);
  const int ns = (qi + 2) >> 1;      // slabs for this qi
  const int jbeg = slab * 2;
  const int jend = min(jbeg + 2, qi + 1);

  const int b = bh >> 4, h = bh & 15;
  const size_t qkbase = (size_t)bh * 131072;
  const int qblk = qi * 128 + w * 32;

  // Q fragments (B-operand): lane holds Q[q = l15 + 16*qt][d = kc*32 + quad*8 + j]
  short8 qf[2][2];
#pragma unroll
  for (int qt = 0; qt < 2; qt++)
#pragma unroll
    for (int kc = 0; kc < 2; kc++)
      qf[qt][kc] = *(const short8*)&Q[qkbase + (size_t)(qblk + qt * 16 + l15) * 64 + kc * 32 + quad * 8];

  float mst[2] = {-3.0e38f, -3.0e38f};
  float lst[2] = {0.0f, 0.0f};
  floatx4 accO[4][2] = {};

  const int krow = t >> 3;
  const int kcol = (((t & 7) ^ (krow & 7)) << 3);
  const u16* gK = Kp + qkbase + (size_t)krow * 64 + kcol;
  const int vrow = t >> 4;
  const int vcol = (((t & 15) ^ vrow) << 3);
  const u16* gV = Vt + qkbase + (size_t)vrow * 2048 + vcol;
  u16* sK = lK + t * 8;
  u16* sV = lV + t * 8;
  u16* myP = lP[w];

  for (int j = jbeg; j < jend; j++) {
    const int j0 = j * 128;
#pragma unroll
    for (int c = 0; c < 4; c++) {
      load_lds16(gK + (size_t)(j0 + c * 32) * 64, sK + c * 2048);
      load_lds16(gV + j0 + c * 16 * 2048, sV + c * 2048);
    }
    __syncthreads();

    // S^T[kv][q] = K * Q^T
    floatx4 accS[8][2] = {};
#pragma unroll
    for (int kvt = 0; kvt < 8; kvt++) {
#pragma unroll
      for (int kc = 0; kc < 2; kc++) {
        const short8 a = *(const short8*)&lK[(kvt * 16 + l15) * 64 + (((kc * 4 + quad) ^ (l15 & 7)) << 3)];
#pragma unroll
        for (int qt = 0; qt < 2; qt++)
          accS[kvt][qt] = __builtin_amdgcn_mfma_f32_16x16x32_bf16(a, qf[qt][kc], accS[kvt][qt], 0, 0, 0);
      }
    }

    if (j == qi) {  // diagonal tile: causal mask
#pragma unroll
      for (int qt = 0; qt < 2; qt++) {
        const int q = qblk + qt * 16 + l15;
#pragma unroll
        for (int kvt = 0; kvt < 8; kvt++)
#pragma unroll
          for (int r = 0; r < 4; r++) {
            const int kv = j0 + kvt * 16 + quad * 4 + r;
            if (kv > q) accS[kvt][qt][r] = -3.0e38f;
          }
      }
    }

    float alpha[2];
#pragma unroll
    for (int qt = 0; qt < 2; qt++) {
      float tm = -3.0e38f;
#pragma unroll
      for (int kvt = 0; kvt < 8; kvt++)
#pragma unroll
        for (int r = 0; r < 4; r++)
          tm = fmaxf(tm, accS[kvt][qt][r]);
      tm = fmaxf(tm, __shfl_xor(tm, 16));
      tm = fmaxf(tm, __shfl_xor(tm, 32));
      const float mnew = fmaxf(mst[qt], tm);
      alpha[qt] = __expf(mst[qt] - mnew);
      mst[qt] = mnew;
      float ts = 0.0f;
      const int prow = (qt * 16 + l15) * 128;
#pragma unroll
      for (int kvt = 0; kvt < 8; kvt++) {
        const float p0 = __expf(accS[kvt][qt][0] - mnew);
        const float p1 = __expf(accS[kvt][qt][1] - mnew);
        const float p2 = __expf(accS[kvt][qt][2] - mnew);
        const float p3 = __expf(accS[kvt][qt][3] - mnew);
        ts += (p0 + p1) + (p2 + p3);
        us4 pk; pk.x = f2bf(p0); pk.y = f2bf(p1); pk.z = f2bf(p2); pk.w = f2bf(p3);
        const int slot = (kvt * 2 + (quad >> 1)) ^ (l15 & 7);
        *(us4*)&myP[prow + slot * 8 + (quad & 1) * 4] = pk;
      }
      ts += __shfl_xor(ts, 16);
      ts += __shfl_xor(ts, 32);
      lst[qt] = lst[qt] * alpha[qt] + ts;
    }

#pragma unroll
    for (int dt = 0; dt < 4; dt++)
#pragma unroll
      for (int qt = 0; qt < 2; qt++)
#pragma unroll
        for (int r = 0; r < 4; r++)
          accO[dt][qt][r] *= alpha[qt];

    asm volatile("s_waitcnt lgkmcnt(0)" ::: "memory");

    // O^T[d][q] += V^T * P^T
#pragma unroll
    for (int kvc = 0; kvc < 4; kvc++) {
      short8 pf[2];
#pragma unroll
      for (int qt = 0; qt < 2; qt++)
        pf[qt] = *(const short8*)&myP[(qt * 16 + l15) * 128 + (((kvc * 4 + quad) ^ (l15 & 7)) << 3)];
#pragma unroll
      for (int dt = 0; dt < 4; dt++) {
        const short8 vf = *(const short8*)&lV[(dt * 16 + l15) * 128 + (((kvc * 4 + quad) ^ l15) << 3)];
#pragma unroll
        for (int qt = 0; qt < 2; qt++)
          accO[dt][qt] = __builtin_amdgcn_mfma_f32_16x16x32_bf16(vf, pf[qt], accO[dt][qt], 0, 0, 0);
      }
    }
    __syncthreads();
  }

  if (ns == 1) {
    // qi <= 1: single slab, write normalized output directly
#pragma unroll
    for (int qt = 0; qt < 2; qt++) {
      const float inv = 1.0f / lst[qt];
      const int q = qblk + qt * 16 + l15;
#pragma unroll
      for (int dt = 0; dt < 4; dt++) {
        us4 o;
        o.x = f2bf(accO[dt][qt][0] * inv);
        o.y = f2bf(accO[dt][qt][1] * inv);
        o.z = f2bf(accO[dt][qt][2] * inv);
        o.w = f2bf(accO[dt][qt][3] * inv);
        *(us4*)&Out[((size_t)b * 2048 + q) * 1024 + h * 64 + dt * 16 + quad * 4] = o;
      }
    }
  } else {
    // partial: O' (unnormalized, bf16) + (m,l) per q-row
    const int slot = bh * 72 + u;   // u == cum(qi)+slab by construction
    u16* op = Opart + (size_t)slot * 8192;
#pragma unroll
    for (int qt = 0; qt < 2; qt++) {
      const int ql = w * 32 + qt * 16 + l15;
#pragma unroll
      for (int dt = 0; dt < 4; dt++) {
        us4 o;
        o.x = f2bf(accO[dt][qt][0]);
        o.y = f2bf(accO[dt][qt][1]);
        o.z = f2bf(accO[dt][qt][2]);
        o.w = f2bf(accO[dt][qt][3]);
        *(us4*)&op[(size_t)ql * 64 + dt * 16 + quad * 4] = o;
      }
      if (quad == 0) {
        f2 v2; v2.x = mst[qt]; v2.y = lst[qt];
        ml[slot * 128 + ql] = v2;
      }
    }
  }
}

// ---------------- split-kv reduction ----------------
// One block per (qi, bh), qi in [2,16): combine ns partials for 128 q x 64 d.
__global__ __launch_bounds__(256) void attn_reduce(const u16* __restrict__ Opart,
                                                   const f2* __restrict__ ml,
                                                   u16* __restrict__ Out) {
  const int qi = blockIdx.x + 2;
  const int bh = blockIdx.y;
  const int b = bh >> 4, h = bh & 15;
  const int p = qi >> 1;
  const int base = bh * 72 + p * (p + 1) + (qi & 1) * (p + 1);
  const int ns = (qi + 2) >> 1;
  const int t = threadIdx.x;
  const int q = t >> 1, dh = (t & 1) * 32;

  float m[8], l[8], wgt[8];
  float mmax = -3.0e38f;
  for (int s = 0; s < ns; s++) {
    f2 v = ml[(base + s) * 128 + q];
    m[s] = v.x; l[s] = v.y;
    mmax = fmaxf(mmax, m[s]);
  }
  float lsum = 0.0f;
  for (int s = 0; s < ns; s++) {
    wgt[s] = __expf(m[s] - mmax);
    lsum += wgt[s] * l[s];
  }
  float acc[32] = {};
  for (int s = 0; s < ns; s++) {
    const u16* src = Opart + ((size_t)(base + s) * 128 + q) * 64 + dh;
    const float ws = wgt[s];
#pragma unroll
    for (int i = 0; i < 8; i++) {
      us4 vv = *(const us4*)&src[i * 4];
      acc[i * 4 + 0] += ws * bf2f(vv.x);
      acc[i * 4 + 1] += ws * bf2f(vv.y);
      acc[i * 4 + 2] += ws * bf2f(vv.z);
      acc[i * 4 + 3] += ws * bf2f(vv.w);
    }
  }
  const float inv = 1.0f / lsum;
  u16* dst = Out + ((size_t)b * 2048 + qi * 128 + q) * 1024 + h * 64 + dh;
#pragma unroll
  for (int i = 0; i < 8; i++) {
    us4 o;
    o.x = f2bf(acc[i * 4 + 0] * inv);
    o.y = f2bf(acc[i * 4 + 1] * inv);
    o.z = f2bf(acc[i * 4 + 2] * inv);
    o.w = f2bf(acc[i * 4 + 3] * inv);
    *(us4*)&dst[i * 4] = o;
  }
}

// ---------------- launcher ----------------
extern "C" void kernel_launch(void* const* d_in, const int* in_sizes, int n_in,
                              void* d_out, int out_size, void* d_ws, size_t ws_size,
                              hipStream_t stream) {
  (void)in_sizes; (void)n_in; (void)out_size; (void)ws_size;
  const float* hidden = (const float*)d_in[0];
  const float* attn_w = (const float*)d_in[1];
  const float* attn_b = (const float*)d_in[2];
  const float* proj_w = (const float*)d_in[3];
  const float* proj_b = (const float*)d_in[4];
  ConvW cw;
  for (int i = 0; i < 9; i++) {
    cw.w[i] = (const float*)d_in[5 + 2 * i];
    cw.b[i] = (const float*)d_in[6 + 2 * i];
  }

  uint8_t* ws = (uint8_t*)d_ws;
  // prologue buffers (dead by attention time -> overlaid by Opart)
  u16* h_bf   = (u16*)(ws + 0);          //  8,388,608 B
  u16* wqkvT  = (u16*)(ws + 8388608);    //  6,291,456 B
  u16* qkvpre = (u16*)(ws + 14680064);   // 25,165,824 B  [3][2][16][2048][64]
  // live through attention
  u16* qpost  = (u16*)(ws + 39845888);   //  8,388,608 B  [2][16][2048][64]
  u16* kpost  = (u16*)(ws + 48234496);   //  8,388,608 B
  u16* vpostT = (u16*)(ws + 56623104);   //  8,388,608 B  [2][16][64][2048]
  u16* attno  = (u16*)(ws + 65011712);   //  8,388,608 B  [2][2048][1024]
  u16* wprojT = (u16*)(ws + 73400320);   //  2,097,152 B  (live till final gemm)
  f2*  ml     = (f2*) (ws + 75497472);   //  2,359,296 B  [2304][128] (m,l)
  u16* Opart  = (u16*)(ws + 0);          // 37,748,736 B  [2304][128][64] overlay

  cvt_f32_bf16<<<4096, 256, 0, stream>>>(hidden, h_bf, 4194304);
  transpose_cvt<<<dim3(96, 32), dim3(32, 8), 0, stream>>>(attn_w, wqkvT, 1024, 3072);
  transpose_cvt<<<dim3(32, 32), dim3(32, 8), 0, stream>>>(proj_w, wprojT, 1024, 1024);
  gemm_bt<0, 128><<<dim3(24, 32), 256, 0, stream>>>(h_bf, wqkvT, attn_b, (void*)qkvpre, 4096, 3072, 1024);
  conv_mix<<<dim3(16, 16, 6), 256, 0, stream>>>(qkvpre, cw, qpost, kpost, vpostT);
  attn_fwd<<<dim3(2304), 256, 0, stream>>>(qpost, kpost, vpostT, attno, Opart, ml);
  attn_reduce<<<dim3(14, 32), 256, 0, stream>>>(Opart, ml, attno);
  gemm_bt<1, 64><<<dim3(16, 32), 256, 0, stream>>>(attno, wprojT, proj_b, d_out, 4096, 1024, 1024);
}

// Round 6
// 296.785 us; speedup vs baseline: 1.0447x; 1.0126x over previous
//
#include <hip/hip_runtime.h>
#include <stdint.h>
#include <math.h>

typedef unsigned short u16;
typedef __attribute__((ext_vector_type(8))) short short8;
typedef __attribute__((ext_vector_type(4))) float floatx4;

#define DEV static __device__ __forceinline__

struct alignas(8) us4 { u16 x, y, z, w; };
struct alignas(16) f4 { float x, y, z, w; };
struct alignas(8) f2 { float x, y; };
struct alignas(8) u32x2 { uint32_t x, y; };

DEV u16 f2bf(float f) {
  uint32_t u = __float_as_uint(f);
  u += 0x7fffu + ((u >> 16) & 1u);
  return (u16)(u >> 16);
}
DEV float bf2f(u16 h) { return __uint_as_float(((uint32_t)h) << 16); }

// pack 2 floats -> 2 bf16 in one u32 (low16 = a). HW pk-cvt when available.
DEV uint32_t pkbf(float a, float b) {
#if __has_builtin(__builtin_amdgcn_cvt_pk_bf16_f32)
  typedef __attribute__((ext_vector_type(2))) __bf16 bf2_t;
  bf2_t v = __builtin_amdgcn_cvt_pk_bf16_f32(a, b);
  uint32_t r; __builtin_memcpy(&r, &v, 4); return r;
#else
  return (uint32_t)f2bf(a) | ((uint32_t)f2bf(b) << 16);
#endif
}

DEV float fexp2(float x) {
#if __has_builtin(__builtin_amdgcn_exp2f)
  return __builtin_amdgcn_exp2f(x);
#else
  return exp2f(x);
#endif
}

DEV void load_lds16(const void* g, void* l) {
  __builtin_amdgcn_global_load_lds((const __attribute__((address_space(1))) void*)g,
                                   (__attribute__((address_space(3))) void*)l, 16, 0, 0);
}

// ---------------- elementwise fp32 -> bf16 ----------------
__global__ void cvt_f32_bf16(const float* __restrict__ in, u16* __restrict__ out, int n) {
  int i = (blockIdx.x * blockDim.x + threadIdx.x) * 4;
  if (i < n) {
    f4 v = *(const f4*)(in + i);
    us4 o; o.x = f2bf(v.x); o.y = f2bf(v.y); o.z = f2bf(v.z); o.w = f2bf(v.w);
    *(us4*)(out + i) = o;
  }
}

// ---------------- transpose + convert: W[K][N] fp32 -> WT[N][K] bf16 ----------------
__global__ void transpose_cvt(const float* __restrict__ in, u16* __restrict__ out, int K, int N) {
  __shared__ float tile[32][33];
  const int n0 = blockIdx.x * 32, k0 = blockIdx.y * 32;
  const int tx = threadIdx.x, ty = threadIdx.y;
  for (int i = ty; i < 32; i += 8)
    tile[i][tx] = in[(size_t)(k0 + i) * N + n0 + tx];
  __syncthreads();
  for (int i = ty; i < 32; i += 8)
    out[(size_t)(n0 + i) * K + k0 + tx] = f2bf(tile[tx][i]);
}

// ---------------- bf16 GEMM, C = A[M,K] * Bt[N,K]^T + bias ----------------
// 1D grid, XCD-locality swizzle: m fastest (stride-8 RR keeps one m-tile's n-uses
// on one XCD), n grouped in supertiles of NGRP tiles. M fixed at 32 m-tiles (4096).
// Operands swapped: lane holds (m=l15, n=quad*4+reg) -> coalesced stores.
template <int EPI, int BN, int NGRP>
__global__ __launch_bounds__(256) void gemm_bt(const u16* __restrict__ A,
                                               const u16* __restrict__ Bt,
                                               const float* __restrict__ bias,
                                               void* __restrict__ outp,
                                               int M, int N, int K) {
  constexpr int NT = BN / 32;
  __shared__ u16 lA[128 * 64];
  __shared__ u16 lB[BN * 64];
  const int t = threadIdx.x;
  const int w = t >> 6, lane = t & 63;
  const int quad = lane >> 4, l15 = lane & 15;
  const int wm = w >> 1, wn = w & 1;
  const int wn_off = wn * (BN / 2);

  const int bid = blockIdx.x;
  const int gsz = 32 * NGRP;
  const int grp = bid / gsz;
  const int r = bid - grp * gsz;
  const int m0 = (r & 31) * 128;
  const int n0 = (grp * NGRP + (r >> 5)) * BN;

  floatx4 acc[4][NT] = {};

  const int srow = t >> 3;
  const int scol = (((t & 7) ^ (srow & 7)) << 3);
  const u16* gA = A + (size_t)(m0 + srow) * K + scol;
  const u16* gB = Bt + (size_t)(n0 + srow) * K + scol;
  u16* sA = lA + t * 8;
  u16* sB = lB + t * 8;
  const size_t rstep = (size_t)32 * K;

  for (int k0 = 0; k0 < K; k0 += 64) {
#pragma unroll
    for (int c = 0; c < 4; c++) load_lds16(gA + c * rstep, sA + c * 2048);
#pragma unroll
    for (int c = 0; c < BN / 32; c++) load_lds16(gB + c * rstep, sB + c * 2048);
    gA += 64; gB += 64;
    __syncthreads();
#pragma unroll
    for (int kc = 0; kc < 2; kc++) {
      short8 af[4], bfr[NT];
#pragma unroll
      for (int mt = 0; mt < 4; mt++)
        af[mt] = *(const short8*)&lA[(wm * 64 + mt * 16 + l15) * 64 + (((kc * 4 + quad) ^ (l15 & 7)) << 3)];
#pragma unroll
      for (int nt = 0; nt < NT; nt++)
        bfr[nt] = *(const short8*)&lB[(wn_off + nt * 16 + l15) * 64 + (((kc * 4 + quad) ^ (l15 & 7)) << 3)];
#pragma unroll
      for (int mt = 0; mt < 4; mt++)
#pragma unroll
        for (int nt = 0; nt < NT; nt++)
          acc[mt][nt] = __builtin_amdgcn_mfma_f32_16x16x32_bf16(bfr[nt], af[mt], acc[mt][nt], 0, 0, 0);
    }
    __syncthreads();
  }

  if (EPI == 0) {
    u16* outq = (u16*)outp;
#pragma unroll
    for (int nt = 0; nt < NT; nt++) {
      const int nb = n0 + wn_off + nt * 16 + quad * 4;
      const f4 bn4 = *(const f4*)&bias[nb];
      const int tensor = nb >> 10, e = nb & 1023;
      const int h = e >> 6, d = e & 63;
      const size_t abase = (size_t)tensor * 4194304 + (size_t)h * 131072 + d;
#pragma unroll
      for (int mt = 0; mt < 4; mt++) {
        const int rr = m0 + wm * 64 + mt * 16 + l15;
        const int b = rr >> 11, s = rr & 2047;
        u32x2 o;
        o.x = pkbf(acc[mt][nt][0] + bn4.x, acc[mt][nt][1] + bn4.y);
        o.y = pkbf(acc[mt][nt][2] + bn4.z, acc[mt][nt][3] + bn4.w);
        *(u32x2*)&outq[abase + (size_t)b * 2097152 + (size_t)s * 64] = o;
      }
    }
  } else {
    float* outf = (float*)outp;
#pragma unroll
    for (int nt = 0; nt < NT; nt++) {
      const int nb = n0 + wn_off + nt * 16 + quad * 4;
      const f4 bn4 = *(const f4*)&bias[nb];
#pragma unroll
      for (int mt = 0; mt < 4; mt++) {
        const int rr = m0 + wm * 64 + mt * 16 + l15;
        f4 o;
        o.x = acc[mt][nt][0] + bn4.x;
        o.y = acc[mt][nt][1] + bn4.y;
        o.z = acc[mt][nt][2] + bn4.z;
        o.w = acc[mt][nt][3] + bn4.w;
        *(f4*)&outf[(size_t)rr * N + nb] = o;
      }
    }
  }
}

// ---------------- causal depthwise conv / head-mix ----------------
struct ConvW { const float* w[9]; const float* b[9]; };

__global__ __launch_bounds__(256) void conv_mix(const u16* __restrict__ qkv, ConvW cw,
                                                u16* __restrict__ qpost,
                                                u16* __restrict__ kpost,
                                                u16* __restrict__ vpostT) {
  __shared__ u16 xt[134 * 68];
  const int t = threadIdx.x;
  const int s0 = blockIdx.x * 128;
  const int h = blockIdx.y;
  const int tz = blockIdx.z;
  const int tensor = tz >> 1, b = tz & 1;
  const u16* src = qkv + (((size_t)tensor * 2 + b) * 16 + h) * 131072;

  for (int idx = t; idx < 134 * 16; idx += 256) {
    const int row = idx >> 4, c4 = (idx & 15) << 2;
    const int s = s0 - 6 + row;
    us4 v = {0, 0, 0, 0};
    if (s >= 0) v = *(const us4*)&src[(size_t)s * 64 + c4];
    *(us4*)&xt[row * 68 + c4] = v;
  }
  __syncthreads();

  const int group = h >> 2;
  const int ksz = group * 2 + 1;
  const float* wp = (group > 0) ? cw.w[tensor * 3 + group - 1] : nullptr;
  const float* bp = (group > 0) ? cw.b[tensor * 3 + group - 1] : nullptr;
  // Q pre-scale: 1/sqrt(64) * log2(e) so attention softmax runs in exp2 domain
  const float qscale = (tensor == 0) ? 0.18033688f : 1.0f;

  if (tensor < 2) {
    u16* outp = (tensor == 0) ? qpost : kpost;
    const size_t ob = (((size_t)b * 16 + h) * 2048 + s0) * 64;
    for (int i = 0; i < 32; i++) {
      const int lin = t + i * 256;
      const int sl = lin >> 6, d = lin & 63;
      float val;
      if (group == 0) {
        val = bf2f(xt[(sl + 6) * 68 + d]);
      } else {
        val = bp[d];
        for (int jj = 0; jj < ksz; jj++)
          val += wp[d * ksz + jj] * bf2f(xt[(sl + 6 - (ksz - 1) + jj) * 68 + d]);
      }
      outp[ob + (size_t)sl * 64 + d] = f2bf(val * qscale);
    }
  } else {
    const size_t ob = ((size_t)b * 16 + h) * 64;
    for (int i = 0; i < 32; i++) {
      const int lin = t + i * 256;
      const int d = lin >> 7, sl = lin & 127;
      float val;
      if (group == 0) {
        val = bf2f(xt[(sl + 6) * 68 + d]);
      } else {
        val = bp[d];
        for (int jj = 0; jj < ksz; jj++)
          val += wp[d * ksz + jj] * bf2f(xt[(sl + 6 - (ksz - 1) + jj) * 68 + d]);
      }
      vpostT[(ob + d) * 2048 + s0 + sl] = f2bf(val);
    }
  }
}

// ---------------- split-kv causal flash attention (exp2-domain softmax) ----------------
// Scores arrive pre-scaled by log2(e)/8 (folded into Q), so softmax uses exp2 directly.
__global__ __launch_bounds__(256) void attn_fwd(const u16* __restrict__ Q,
                                                const u16* __restrict__ Kp,
                                                const u16* __restrict__ Vt,
                                                u16* __restrict__ Out,
                                                u16* __restrict__ Opart,
                                                f2* __restrict__ ml) {
  __shared__ u16 lK[128 * 64];       // [kv][d]
  __shared__ u16 lV[64 * 128];       // [d][kv]
  __shared__ u16 lP[4][32 * 128];    // per wave: [q_local][kv]
  const int t = threadIdx.x;
  const int w = t >> 6, lane = t & 63;
  const int quad = lane >> 4, l15 = lane & 15;

  const int lin = blockIdx.x;
  const int xcd = lin & 7;
  const int idx = lin >> 3;          // 0..287
  const int grp = idx / 72;          // 0..3
  const int u = idx - grp * 72;      // 0..71
  const int bh = grp * 8 + xcd;
  int p = (int)(0.5f * (sqrtf(4.0f * (float)u + 1.0f) - 1.0f));
  if ((p + 1) * (p + 2) <= u) p++;
  if (p * (p + 1) > u) p--;
  const int v = u - p * (p + 1);
  const int qi = 2 * p + (v >= p + 1 ? 1 : 0);
  const int slab = v - (v >= p + 1 ? p + 1 : 0);
  const int ns = (qi + 2) >> 1;
  const int jbeg = slab * 2;
  const int jend = min(jbeg + 2, qi + 1);

  const int b = bh >> 4, h = bh & 15;
  const size_t qkbase = (size_t)bh * 131072;
  const int qblk = qi * 128 + w * 32;

  short8 qf[2][2];
#pragma unroll
  for (int qt = 0; qt < 2; qt++)
#pragma unroll
    for (int kc = 0; kc < 2; kc++)
      qf[qt][kc] = *(const short8*)&Q[qkbase + (size_t)(qblk + qt * 16 + l15) * 64 + kc * 32 + quad * 8];

  float mst[2] = {-3.0e38f, -3.0e38f};
  float lst[2] = {0.0f, 0.0f};
  floatx4 accO[4][2] = {};

  const int krow = t >> 3;
  const int kcol = (((t & 7) ^ (krow & 7)) << 3);
  const u16* gK = Kp + qkbase + (size_t)krow * 64 + kcol;
  const int vrow = t >> 4;
  const int vcol = (((t & 15) ^ vrow) << 3);
  const u16* gV = Vt + qkbase + (size_t)vrow * 2048 + vcol;
  u16* sK = lK + t * 8;
  u16* sV = lV + t * 8;
  u16* myP = lP[w];

  for (int j = jbeg; j < jend; j++) {
    const int j0 = j * 128;
#pragma unroll
    for (int c = 0; c < 4; c++) {
      load_lds16(gK + (size_t)(j0 + c * 32) * 64, sK + c * 2048);
      load_lds16(gV + j0 + c * 16 * 2048, sV + c * 2048);
    }
    __syncthreads();

    floatx4 accS[8][2] = {};
#pragma unroll
    for (int kvt = 0; kvt < 8; kvt++) {
#pragma unroll
      for (int kc = 0; kc < 2; kc++) {
        const short8 a = *(const short8*)&lK[(kvt * 16 + l15) * 64 + (((kc * 4 + quad) ^ (l15 & 7)) << 3)];
#pragma unroll
        for (int qt = 0; qt < 2; qt++)
          accS[kvt][qt] = __builtin_amdgcn_mfma_f32_16x16x32_bf16(a, qf[qt][kc], accS[kvt][qt], 0, 0, 0);
      }
    }

    if (j == qi) {
#pragma unroll
      for (int qt = 0; qt < 2; qt++) {
        const int q = qblk + qt * 16 + l15;
#pragma unroll
        for (int kvt = 0; kvt < 8; kvt++)
#pragma unroll
          for (int r = 0; r < 4; r++) {
            const int kv = j0 + kvt * 16 + quad * 4 + r;
            if (kv > q) accS[kvt][qt][r] = -3.0e38f;
          }
      }
    }

    float alpha[2];
#pragma unroll
    for (int qt = 0; qt < 2; qt++) {
      float tm = -3.0e38f;
#pragma unroll
      for (int kvt = 0; kvt < 8; kvt++)
#pragma unroll
        for (int r = 0; r < 4; r++)
          tm = fmaxf(tm, accS[kvt][qt][r]);
      tm = fmaxf(tm, __shfl_xor(tm, 16));
      tm = fmaxf(tm, __shfl_xor(tm, 32));
      const float mnew = fmaxf(mst[qt], tm);
      alpha[qt] = fexp2(mst[qt] - mnew);
      mst[qt] = mnew;
      float ts = 0.0f;
      const int prow = (qt * 16 + l15) * 128;
#pragma unroll
      for (int kvt = 0; kvt < 8; kvt++) {
        const float p0 = fexp2(accS[kvt][qt][0] - mnew);
        const float p1 = fexp2(accS[kvt][qt][1] - mnew);
        const float p2 = fexp2(accS[kvt][qt][2] - mnew);
        const float p3 = fexp2(accS[kvt][qt][3] - mnew);
        ts += (p0 + p1) + (p2 + p3);
        u32x2 pk;
        pk.x = pkbf(p0, p1);
        pk.y = pkbf(p2, p3);
        const int slot = (kvt * 2 + (quad >> 1)) ^ (l15 & 7);
        *(u32x2*)&myP[prow + slot * 8 + (quad & 1) * 4] = pk;
      }
      ts += __shfl_xor(ts, 16);
      ts += __shfl_xor(ts, 32);
      lst[qt] = lst[qt] * alpha[qt] + ts;
    }

#pragma unroll
    for (int dt = 0; dt < 4; dt++)
#pragma unroll
      for (int qt = 0; qt < 2; qt++)
#pragma unroll
        for (int r = 0; r < 4; r++)
          accO[dt][qt][r] *= alpha[qt];

    asm volatile("s_waitcnt lgkmcnt(0)" ::: "memory");

#pragma unroll
    for (int kvc = 0; kvc < 4; kvc++) {
      short8 pf[2];
#pragma unroll
      for (int qt = 0; qt < 2; qt++)
        pf[qt] = *(const short8*)&myP[(qt * 16 + l15) * 128 + (((kvc * 4 + quad) ^ (l15 & 7)) << 3)];
#pragma unroll
      for (int dt = 0; dt < 4; dt++) {
        const short8 vf = *(const short8*)&lV[(dt * 16 + l15) * 128 + (((kvc * 4 + quad) ^ l15) << 3)];
#pragma unroll
        for (int qt = 0; qt < 2; qt++)
          accO[dt][qt] = __builtin_amdgcn_mfma_f32_16x16x32_bf16(vf, pf[qt], accO[dt][qt], 0, 0, 0);
      }
    }
    __syncthreads();
  }

  if (ns == 1) {
#pragma unroll
    for (int qt = 0; qt < 2; qt++) {
      const float inv = 1.0f / lst[qt];
      const int q = qblk + qt * 16 + l15;
#pragma unroll
      for (int dt = 0; dt < 4; dt++) {
        u32x2 o;
        o.x = pkbf(accO[dt][qt][0] * inv, accO[dt][qt][1] * inv);
        o.y = pkbf(accO[dt][qt][2] * inv, accO[dt][qt][3] * inv);
        *(u32x2*)&Out[((size_t)b * 2048 + q) * 1024 + h * 64 + dt * 16 + quad * 4] = o;
      }
    }
  } else {
    const int slot = bh * 72 + u;
    u16* op = Opart + (size_t)slot * 8192;
#pragma unroll
    for (int qt = 0; qt < 2; qt++) {
      const int ql = w * 32 + qt * 16 + l15;
#pragma unroll
      for (int dt = 0; dt < 4; dt++) {
        u32x2 o;
        o.x = pkbf(accO[dt][qt][0], accO[dt][qt][1]);
        o.y = pkbf(accO[dt][qt][2], accO[dt][qt][3]);
        *(u32x2*)&op[(size_t)ql * 64 + dt * 16 + quad * 4] = o;
      }
      if (quad == 0) {
        f2 v2; v2.x = mst[qt]; v2.y = lst[qt];
        ml[slot * 128 + ql] = v2;
      }
    }
  }
}

// ---------------- split-kv reduction (exp2 domain) ----------------
__global__ __launch_bounds__(256) void attn_reduce(const u16* __restrict__ Opart,
                                                   const f2* __restrict__ ml,
                                                   u16* __restrict__ Out) {
  const int qi = blockIdx.x + 2;
  const int bh = blockIdx.y;
  const int b = bh >> 4, h = bh & 15;
  const int p = qi >> 1;
  const int base = bh * 72 + p * (p + 1) + (qi & 1) * (p + 1);
  const int ns = (qi + 2) >> 1;
  const int t = threadIdx.x;
  const int q = t >> 1, dh = (t & 1) * 32;

  float m[8], l[8], wgt[8];
  float mmax = -3.0e38f;
  for (int s = 0; s < ns; s++) {
    f2 v = ml[(base + s) * 128 + q];
    m[s] = v.x; l[s] = v.y;
    mmax = fmaxf(mmax, m[s]);
  }
  float lsum = 0.0f;
  for (int s = 0; s < ns; s++) {
    wgt[s] = fexp2(m[s] - mmax);
    lsum += wgt[s] * l[s];
  }
  float acc[32] = {};
  for (int s = 0; s < ns; s++) {
    const u16* src = Opart + ((size_t)(base + s) * 128 + q) * 64 + dh;
    const float ws = wgt[s];
#pragma unroll
    for (int i = 0; i < 8; i++) {
      us4 vv = *(const us4*)&src[i * 4];
      acc[i * 4 + 0] += ws * bf2f(vv.x);
      acc[i * 4 + 1] += ws * bf2f(vv.y);
      acc[i * 4 + 2] += ws * bf2f(vv.z);
      acc[i * 4 + 3] += ws * bf2f(vv.w);
    }
  }
  const float inv = 1.0f / lsum;
  u16* dst = Out + ((size_t)b * 2048 + qi * 128 + q) * 1024 + h * 64 + dh;
#pragma unroll
  for (int i = 0; i < 8; i++) {
    u32x2 o;
    o.x = pkbf(acc[i * 4 + 0] * inv, acc[i * 4 + 1] * inv);
    o.y = pkbf(acc[i * 4 + 2] * inv, acc[i * 4 + 3] * inv);
    *(u32x2*)&dst[i * 4] = o;
  }
}

// ---------------- launcher ----------------
extern "C" void kernel_launch(void* const* d_in, const int* in_sizes, int n_in,
                              void* d_out, int out_size, void* d_ws, size_t ws_size,
                              hipStream_t stream) {
  (void)in_sizes; (void)n_in; (void)out_size; (void)ws_size;
  const float* hidden = (const float*)d_in[0];
  const float* attn_w = (const float*)d_in[1];
  const float* attn_b = (const float*)d_in[2];
  const float* proj_w = (const float*)d_in[3];
  const float* proj_b = (const float*)d_in[4];
  ConvW cw;
  for (int i = 0; i < 9; i++) {
    cw.w[i] = (const float*)d_in[5 + 2 * i];
    cw.b[i] = (const float*)d_in[6 + 2 * i];
  }

  uint8_t* ws = (uint8_t*)d_ws;
  u16* h_bf   = (u16*)(ws + 0);          //  8,388,608 B
  u16* wqkvT  = (u16*)(ws + 8388608);    //  6,291,456 B
  u16* qkvpre = (u16*)(ws + 14680064);   // 25,165,824 B  [3][2][16][2048][64]
  u16* qpost  = (u16*)(ws + 39845888);   //  8,388,608 B  [2][16][2048][64]
  u16* kpost  = (u16*)(ws + 48234496);   //  8,388,608 B
  u16* vpostT = (u16*)(ws + 56623104);   //  8,388,608 B  [2][16][64][2048]
  u16* attno  = (u16*)(ws + 65011712);   //  8,388,608 B  [2][2048][1024]
  u16* wprojT = (u16*)(ws + 73400320);   //  2,097,152 B
  f2*  ml     = (f2*) (ws + 75497472);   //  2,359,296 B  [2304][128] (m,l)
  u16* Opart  = (u16*)(ws + 0);          // 37,748,736 B  overlay on prologue bufs

  cvt_f32_bf16<<<4096, 256, 0, stream>>>(hidden, h_bf, 4194304);
  transpose_cvt<<<dim3(96, 32), dim3(32, 8), 0, stream>>>(attn_w, wqkvT, 1024, 3072);
  transpose_cvt<<<dim3(32, 32), dim3(32, 8), 0, stream>>>(proj_w, wprojT, 1024, 1024);
  gemm_bt<0, 128, 6><<<768, 256, 0, stream>>>(h_bf, wqkvT, attn_b, (void*)qkvpre, 4096, 3072, 1024);
  conv_mix<<<dim3(16, 16, 6), 256, 0, stream>>>(qkvpre, cw, qpost, kpost, vpostT);
  attn_fwd<<<dim3(2304), 256, 0, stream>>>(qpost, kpost, vpostT, attno, Opart, ml);
  attn_reduce<<<dim3(14, 32), 256, 0, stream>>>(Opart, ml, attno);
  gemm_bt<1, 64, 8><<<512, 256, 0, stream>>>(attno, wprojT, proj_b, d_out, 4096, 1024, 1024);
}

// Round 7
// 260.700 us; speedup vs baseline: 1.1893x; 1.1384x over previous
//
#include <hip/hip_runtime.h>
#include <stdint.h>
#include <math.h>

typedef unsigned short u16;
typedef __attribute__((ext_vector_type(8))) short short8;
typedef __attribute__((ext_vector_type(4))) float floatx4;

#define DEV static __device__ __forceinline__

struct alignas(8) us4 { u16 x, y, z, w; };
struct alignas(16) us8 { u16 v[8]; };
struct alignas(16) f4 { float x, y, z, w; };
struct alignas(8) f2 { float x, y; };
struct alignas(8) u32x2 { uint32_t x, y; };

DEV u16 f2bf(float f) {
  uint32_t u = __float_as_uint(f);
  u += 0x7fffu + ((u >> 16) & 1u);
  return (u16)(u >> 16);
}
DEV float bf2f(u16 h) { return __uint_as_float(((uint32_t)h) << 16); }

DEV uint32_t pkbf(float a, float b) {
#if __has_builtin(__builtin_amdgcn_cvt_pk_bf16_f32)
  typedef __attribute__((ext_vector_type(2))) __bf16 bf2_t;
  bf2_t v = __builtin_amdgcn_cvt_pk_bf16_f32(a, b);
  uint32_t r; __builtin_memcpy(&r, &v, 4); return r;
#else
  return (uint32_t)f2bf(a) | ((uint32_t)f2bf(b) << 16);
#endif
}

DEV float fexp2(float x) {
#if __has_builtin(__builtin_amdgcn_exp2f)
  return __builtin_amdgcn_exp2f(x);
#else
  return exp2f(x);
#endif
}

DEV void load_lds16(const void* g, void* l) {
  __builtin_amdgcn_global_load_lds((const __attribute__((address_space(1))) void*)g,
                                   (__attribute__((address_space(3))) void*)l, 16, 0, 0);
}

// ---------------- elementwise fp32 -> bf16 ----------------
__global__ void cvt_f32_bf16(const float* __restrict__ in, u16* __restrict__ out, int n) {
  int i = (blockIdx.x * blockDim.x + threadIdx.x) * 4;
  if (i < n) {
    f4 v = *(const f4*)(in + i);
    us4 o; o.x = f2bf(v.x); o.y = f2bf(v.y); o.z = f2bf(v.z); o.w = f2bf(v.w);
    *(us4*)(out + i) = o;
  }
}

// ---------------- transpose + convert: W[K][N] fp32 -> WT[N][K] bf16 ----------------
__global__ void transpose_cvt(const float* __restrict__ in, u16* __restrict__ out, int K, int N) {
  __shared__ float tile[32][33];
  const int n0 = blockIdx.x * 32, k0 = blockIdx.y * 32;
  const int tx = threadIdx.x, ty = threadIdx.y;
  for (int i = ty; i < 32; i += 8)
    tile[i][tx] = in[(size_t)(k0 + i) * N + n0 + tx];
  __syncthreads();
  for (int i = ty; i < 32; i += 8)
    out[(size_t)(n0 + i) * K + k0 + tx] = f2bf(tile[tx][i]);
}

// ---------------- bf16 GEMM, C = A[M,K] * Bt[N,K]^T + bias ----------------
template <int EPI, int BN, int NGRP>
__global__ __launch_bounds__(256) void gemm_bt(const u16* __restrict__ A,
                                               const u16* __restrict__ Bt,
                                               const float* __restrict__ bias,
                                               void* __restrict__ outp,
                                               int M, int N, int K) {
  constexpr int NT = BN / 32;
  __shared__ u16 lA[128 * 64];
  __shared__ u16 lB[BN * 64];
  const int t = threadIdx.x;
  const int w = t >> 6, lane = t & 63;
  const int quad = lane >> 4, l15 = lane & 15;
  const int wm = w >> 1, wn = w & 1;
  const int wn_off = wn * (BN / 2);

  const int bid = blockIdx.x;
  const int gsz = 32 * NGRP;
  const int grp = bid / gsz;
  const int r = bid - grp * gsz;
  const int m0 = (r & 31) * 128;
  const int n0 = (grp * NGRP + (r >> 5)) * BN;

  floatx4 acc[4][NT] = {};

  const int srow = t >> 3;
  const int scol = (((t & 7) ^ (srow & 7)) << 3);
  const u16* gA = A + (size_t)(m0 + srow) * K + scol;
  const u16* gB = Bt + (size_t)(n0 + srow) * K + scol;
  u16* sA = lA + t * 8;
  u16* sB = lB + t * 8;
  const size_t rstep = (size_t)32 * K;

  for (int k0 = 0; k0 < K; k0 += 64) {
#pragma unroll
    for (int c = 0; c < 4; c++) load_lds16(gA + c * rstep, sA + c * 2048);
#pragma unroll
    for (int c = 0; c < BN / 32; c++) load_lds16(gB + c * rstep, sB + c * 2048);
    gA += 64; gB += 64;
    __syncthreads();
#pragma unroll
    for (int kc = 0; kc < 2; kc++) {
      short8 af[4], bfr[NT];
#pragma unroll
      for (int mt = 0; mt < 4; mt++)
        af[mt] = *(const short8*)&lA[(wm * 64 + mt * 16 + l15) * 64 + (((kc * 4 + quad) ^ (l15 & 7)) << 3)];
#pragma unroll
      for (int nt = 0; nt < NT; nt++)
        bfr[nt] = *(const short8*)&lB[(wn_off + nt * 16 + l15) * 64 + (((kc * 4 + quad) ^ (l15 & 7)) << 3)];
#pragma unroll
      for (int mt = 0; mt < 4; mt++)
#pragma unroll
        for (int nt = 0; nt < NT; nt++)
          acc[mt][nt] = __builtin_amdgcn_mfma_f32_16x16x32_bf16(bfr[nt], af[mt], acc[mt][nt], 0, 0, 0);
    }
    __syncthreads();
  }

  if (EPI == 0) {
    u16* outq = (u16*)outp;
#pragma unroll
    for (int nt = 0; nt < NT; nt++) {
      const int nb = n0 + wn_off + nt * 16 + quad * 4;
      const f4 bn4 = *(const f4*)&bias[nb];
      const int tensor = nb >> 10, e = nb & 1023;
      const int h = e >> 6, d = e & 63;
      const size_t abase = (size_t)tensor * 4194304 + (size_t)h * 131072 + d;
#pragma unroll
      for (int mt = 0; mt < 4; mt++) {
        const int rr = m0 + wm * 64 + mt * 16 + l15;
        const int b = rr >> 11, s = rr & 2047;
        u32x2 o;
        o.x = pkbf(acc[mt][nt][0] + bn4.x, acc[mt][nt][1] + bn4.y);
        o.y = pkbf(acc[mt][nt][2] + bn4.z, acc[mt][nt][3] + bn4.w);
        *(u32x2*)&outq[abase + (size_t)b * 2097152 + (size_t)s * 64] = o;
      }
    }
  } else {
    float* outf = (float*)outp;
#pragma unroll
    for (int nt = 0; nt < NT; nt++) {
      const int nb = n0 + wn_off + nt * 16 + quad * 4;
      const f4 bn4 = *(const f4*)&bias[nb];
#pragma unroll
      for (int mt = 0; mt < 4; mt++) {
        const int rr = m0 + wm * 64 + mt * 16 + l15;
        f4 o;
        o.x = acc[mt][nt][0] + bn4.x;
        o.y = acc[mt][nt][1] + bn4.y;
        o.z = acc[mt][nt][2] + bn4.z;
        o.w = acc[mt][nt][3] + bn4.w;
        *(f4*)&outf[(size_t)rr * N + nb] = o;
      }
    }
  }
}

// ---------------- causal depthwise conv / head-mix (register sliding window) ----------------
struct ConvW { const float* w[9]; const float* b[9]; };

// Compute 32 consecutive outputs for column d with a K-tap register window.
// xt rows are s-6 .. s+127 (halo 6). Output row i corresponds to s0+sl0+i.
template <int K>
DEV void conv_run(const u16* xt, int sl0, int d, const float* wp, const float* bp,
                  float qscale, float* out32) {
  float wr[K];
#pragma unroll
  for (int j = 0; j < K; j++) wr[j] = wp[d * K + j];
  const float br = bp[d];
  float win[K];
#pragma unroll
  for (int m = 1; m < K; m++) win[m] = bf2f(xt[(sl0 + 6 - K + m) * 68 + d]);
#pragma unroll
  for (int i = 0; i < 32; i++) {
#pragma unroll
    for (int m = 0; m < K - 1; m++) win[m] = win[m + 1];
    win[K - 1] = bf2f(xt[(sl0 + 6 + i) * 68 + d]);
    float val = br;
#pragma unroll
    for (int j = 0; j < K; j++) val += wr[j] * win[j];
    out32[i] = val * qscale;
  }
}

__global__ __launch_bounds__(256) void conv_mix(const u16* __restrict__ qkv, ConvW cw,
                                                u16* __restrict__ qpost,
                                                u16* __restrict__ kpost,
                                                u16* __restrict__ vpostT) {
  __shared__ u16 xt[134 * 68];   // [s-halo 134][d 64 +4 pad]
  __shared__ u16 yt[64 * 136];   // V transpose staging [d][sl 128 +8 pad]
  const int t = threadIdx.x;
  const int s0 = blockIdx.x * 128;
  const int h = blockIdx.y;
  const int tz = blockIdx.z;
  const int tensor = tz >> 1, b = tz & 1;
  const u16* src = qkv + (((size_t)tensor * 2 + b) * 16 + h) * 131072;

  for (int idx = t; idx < 134 * 16; idx += 256) {
    const int row = idx >> 4, c4 = (idx & 15) << 2;
    const int s = s0 - 6 + row;
    us4 v = {0, 0, 0, 0};
    if (s >= 0) v = *(const us4*)&src[(size_t)s * 64 + c4];
    *(us4*)&xt[row * 68 + c4] = v;
  }
  __syncthreads();

  const int group = h >> 2;
  const float* wp = (group > 0) ? cw.w[tensor * 3 + group - 1] : nullptr;
  const float* bp = (group > 0) ? cw.b[tensor * 3 + group - 1] : nullptr;
  // Q pre-scale: 1/sqrt(64) * log2(e) for exp2-domain softmax
  const float qscale = (tensor == 0) ? 0.18033688f : 1.0f;

  const int d = t & 63;          // fixed per thread -> weights/bias loop-invariant
  const int sl0 = (t >> 6) * 32; // 32 consecutive rows per thread

  float out32[32];
  if (group == 0) {
#pragma unroll
    for (int i = 0; i < 32; i++)
      out32[i] = bf2f(xt[(sl0 + 6 + i) * 68 + d]) * qscale;
  } else if (group == 1) {
    conv_run<3>(xt, sl0, d, wp, bp, qscale, out32);
  } else if (group == 2) {
    conv_run<5>(xt, sl0, d, wp, bp, qscale, out32);
  } else {
    conv_run<7>(xt, sl0, d, wp, bp, qscale, out32);
  }

  if (tensor < 2) {
    u16* outp = (tensor == 0) ? qpost : kpost;
    const size_t ob = (((size_t)b * 16 + h) * 2048 + s0) * 64;
#pragma unroll
    for (int i = 0; i < 32; i++)
      outp[ob + (size_t)(sl0 + i) * 64 + d] = f2bf(out32[i]);  // wave: 64 consec d, coalesced
  } else {
    // stage transposed into LDS, then vectorized b128 stores
#pragma unroll
    for (int i = 0; i < 32; i++)
      yt[d * 136 + sl0 + i] = f2bf(out32[i]);
    __syncthreads();
    const size_t ob = ((size_t)b * 16 + h) * 64;
    const int sl = (t & 15) * 8;
#pragma unroll
    for (int pass = 0; pass < 4; pass++) {
      const int dd = (t >> 4) + pass * 16;
      us8 vv = *(const us8*)&yt[dd * 136 + sl];
      *(us8*)&vpostT[(ob + dd) * 2048 + s0 + sl] = vv;  // 16 lanes x 16B = 256B segments
    }
  }
}

// ---------------- split-kv causal flash attention (exp2-domain softmax) ----------------
__global__ __launch_bounds__(256) void attn_fwd(const u16* __restrict__ Q,
                                                const u16* __restrict__ Kp,
                                                const u16* __restrict__ Vt,
                                                u16* __restrict__ Out,
                                                u16* __restrict__ Opart,
                                                f2* __restrict__ ml) {
  __shared__ u16 lK[128 * 64];       // [kv][d]
  __shared__ u16 lV[64 * 128];       // [d][kv]
  __shared__ u16 lP[4][32 * 128];    // per wave: [q_local][kv]
  const int t = threadIdx.x;
  const int w = t >> 6, lane = t & 63;
  const int quad = lane >> 4, l15 = lane & 15;

  const int lin = blockIdx.x;
  const int xcd = lin & 7;
  const int idx = lin >> 3;          // 0..287
  const int grp = idx / 72;          // 0..3
  const int u = idx - grp * 72;      // 0..71
  const int bh = grp * 8 + xcd;
  int p = (int)(0.5f * (sqrtf(4.0f * (float)u + 1.0f) - 1.0f));
  if ((p + 1) * (p + 2) <= u) p++;
  if (p * (p + 1) > u) p--;
  const int v = u - p * (p + 1);
  const int qi = 2 * p + (v >= p + 1 ? 1 : 0);
  const int slab = v - (v >= p + 1 ? p + 1 : 0);
  const int ns = (qi + 2) >> 1;
  const int jbeg = slab * 2;
  const int jend = min(jbeg + 2, qi + 1);

  const int b = bh >> 4, h = bh & 15;
  const size_t qkbase = (size_t)bh * 131072;
  const int qblk = qi * 128 + w * 32;

  short8 qf[2][2];
#pragma unroll
  for (int qt = 0; qt < 2; qt++)
#pragma unroll
    for (int kc = 0; kc < 2; kc++)
      qf[qt][kc] = *(const short8*)&Q[qkbase + (size_t)(qblk + qt * 16 + l15) * 64 + kc * 32 + quad * 8];

  float mst[2] = {-3.0e38f, -3.0e38f};
  float lst[2] = {0.0f, 0.0f};
  floatx4 accO[4][2] = {};

  const int krow = t >> 3;
  const int kcol = (((t & 7) ^ (krow & 7)) << 3);
  const u16* gK = Kp + qkbase + (size_t)krow * 64 + kcol;
  const int vrow = t >> 4;
  const int vcol = (((t & 15) ^ vrow) << 3);
  const u16* gV = Vt + qkbase + (size_t)vrow * 2048 + vcol;
  u16* sK = lK + t * 8;
  u16* sV = lV + t * 8;
  u16* myP = lP[w];

  for (int j = jbeg; j < jend; j++) {
    const int j0 = j * 128;
#pragma unroll
    for (int c = 0; c < 4; c++) {
      load_lds16(gK + (size_t)(j0 + c * 32) * 64, sK + c * 2048);
      load_lds16(gV + j0 + c * 16 * 2048, sV + c * 2048);
    }
    __syncthreads();

    floatx4 accS[8][2] = {};
#pragma unroll
    for (int kvt = 0; kvt < 8; kvt++) {
#pragma unroll
      for (int kc = 0; kc < 2; kc++) {
        const short8 a = *(const short8*)&lK[(kvt * 16 + l15) * 64 + (((kc * 4 + quad) ^ (l15 & 7)) << 3)];
#pragma unroll
        for (int qt = 0; qt < 2; qt++)
          accS[kvt][qt] = __builtin_amdgcn_mfma_f32_16x16x32_bf16(a, qf[qt][kc], accS[kvt][qt], 0, 0, 0);
      }
    }

    if (j == qi) {
#pragma unroll
      for (int qt = 0; qt < 2; qt++) {
        const int q = qblk + qt * 16 + l15;
#pragma unroll
        for (int kvt = 0; kvt < 8; kvt++)
#pragma unroll
          for (int r = 0; r < 4; r++) {
            const int kv = j0 + kvt * 16 + quad * 4 + r;
            if (kv > q) accS[kvt][qt][r] = -3.0e38f;
          }
      }
    }

    float alpha[2];
#pragma unroll
    for (int qt = 0; qt < 2; qt++) {
      float tm = -3.0e38f;
#pragma unroll
      for (int kvt = 0; kvt < 8; kvt++)
#pragma unroll
        for (int r = 0; r < 4; r++)
          tm = fmaxf(tm, accS[kvt][qt][r]);
      tm = fmaxf(tm, __shfl_xor(tm, 16));
      tm = fmaxf(tm, __shfl_xor(tm, 32));
      const float mnew = fmaxf(mst[qt], tm);
      alpha[qt] = fexp2(mst[qt] - mnew);
      mst[qt] = mnew;
      float ts = 0.0f;
      const int prow = (qt * 16 + l15) * 128;
#pragma unroll
      for (int kvt = 0; kvt < 8; kvt++) {
        const float p0 = fexp2(accS[kvt][qt][0] - mnew);
        const float p1 = fexp2(accS[kvt][qt][1] - mnew);
        const float p2 = fexp2(accS[kvt][qt][2] - mnew);
        const float p3 = fexp2(accS[kvt][qt][3] - mnew);
        ts += (p0 + p1) + (p2 + p3);
        u32x2 pk;
        pk.x = pkbf(p0, p1);
        pk.y = pkbf(p2, p3);
        const int slot = (kvt * 2 + (quad >> 1)) ^ (l15 & 7);
        *(u32x2*)&myP[prow + slot * 8 + (quad & 1) * 4] = pk;
      }
      ts += __shfl_xor(ts, 16);
      ts += __shfl_xor(ts, 32);
      lst[qt] = lst[qt] * alpha[qt] + ts;
    }

#pragma unroll
    for (int dt = 0; dt < 4; dt++)
#pragma unroll
      for (int qt = 0; qt < 2; qt++)
#pragma unroll
        for (int r = 0; r < 4; r++)
          accO[dt][qt][r] *= alpha[qt];

    asm volatile("s_waitcnt lgkmcnt(0)" ::: "memory");

#pragma unroll
    for (int kvc = 0; kvc < 4; kvc++) {
      short8 pf[2];
#pragma unroll
      for (int qt = 0; qt < 2; qt++)
        pf[qt] = *(const short8*)&myP[(qt * 16 + l15) * 128 + (((kvc * 4 + quad) ^ (l15 & 7)) << 3)];
#pragma unroll
      for (int dt = 0; dt < 4; dt++) {
        const short8 vf = *(const short8*)&lV[(dt * 16 + l15) * 128 + (((kvc * 4 + quad) ^ l15) << 3)];
#pragma unroll
        for (int qt = 0; qt < 2; qt++)
          accO[dt][qt] = __builtin_amdgcn_mfma_f32_16x16x32_bf16(vf, pf[qt], accO[dt][qt], 0, 0, 0);
      }
    }
    __syncthreads();
  }

  if (ns == 1) {
#pragma unroll
    for (int qt = 0; qt < 2; qt++) {
      const float inv = 1.0f / lst[qt];
      const int q = qblk + qt * 16 + l15;
#pragma unroll
      for (int dt = 0; dt < 4; dt++) {
        u32x2 o;
        o.x = pkbf(accO[dt][qt][0] * inv, accO[dt][qt][1] * inv);
        o.y = pkbf(accO[dt][qt][2] * inv, accO[dt][qt][3] * inv);
        *(u32x2*)&Out[((size_t)b * 2048 + q) * 1024 + h * 64 + dt * 16 + quad * 4] = o;
      }
    }
  } else {
    const int slot = bh * 72 + u;
    u16* op = Opart + (size_t)slot * 8192;
#pragma unroll
    for (int qt = 0; qt < 2; qt++) {
      const int ql = w * 32 + qt * 16 + l15;
#pragma unroll
      for (int dt = 0; dt < 4; dt++) {
        u32x2 o;
        o.x = pkbf(accO[dt][qt][0], accO[dt][qt][1]);
        o.y = pkbf(accO[dt][qt][2], accO[dt][qt][3]);
        *(u32x2*)&op[(size_t)ql * 64 + dt * 16 + quad * 4] = o;
      }
      if (quad == 0) {
        f2 v2; v2.x = mst[qt]; v2.y = lst[qt];
        ml[slot * 128 + ql] = v2;
      }
    }
  }
}

// ---------------- split-kv reduction (exp2 domain) ----------------
__global__ __launch_bounds__(256) void attn_reduce(const u16* __restrict__ Opart,
                                                   const f2* __restrict__ ml,
                                                   u16* __restrict__ Out) {
  const int qi = blockIdx.x + 2;
  const int bh = blockIdx.y;
  const int b = bh >> 4, h = bh & 15;
  const int p = qi >> 1;
  const int base = bh * 72 + p * (p + 1) + (qi & 1) * (p + 1);
  const int ns = (qi + 2) >> 1;
  const int t = threadIdx.x;
  const int q = t >> 1, dh = (t & 1) * 32;

  float m[8], l[8], wgt[8];
  float mmax = -3.0e38f;
  for (int s = 0; s < ns; s++) {
    f2 v = ml[(base + s) * 128 + q];
    m[s] = v.x; l[s] = v.y;
    mmax = fmaxf(mmax, m[s]);
  }
  float lsum = 0.0f;
  for (int s = 0; s < ns; s++) {
    wgt[s] = fexp2(m[s] - mmax);
    lsum += wgt[s] * l[s];
  }
  float acc[32] = {};
  for (int s = 0; s < ns; s++) {
    const u16* src = Opart + ((size_t)(base + s) * 128 + q) * 64 + dh;
    const float ws = wgt[s];
#pragma unroll
    for (int i = 0; i < 8; i++) {
      us4 vv = *(const us4*)&src[i * 4];
      acc[i * 4 + 0] += ws * bf2f(vv.x);
      acc[i * 4 + 1] += ws * bf2f(vv.y);
      acc[i * 4 + 2] += ws * bf2f(vv.z);
      acc[i * 4 + 3] += ws * bf2f(vv.w);
    }
  }
  const float inv = 1.0f / lsum;
  u16* dst = Out + ((size_t)b * 2048 + qi * 128 + q) * 1024 + h * 64 + dh;
#pragma unroll
  for (int i = 0; i < 8; i++) {
    u32x2 o;
    o.x = pkbf(acc[i * 4 + 0] * inv, acc[i * 4 + 1] * inv);
    o.y = pkbf(acc[i * 4 + 2] * inv, acc[i * 4 + 3] * inv);
    *(u32x2*)&dst[i * 4] = o;
  }
}

// ---------------- launcher ----------------
extern "C" void kernel_launch(void* const* d_in, const int* in_sizes, int n_in,
                              void* d_out, int out_size, void* d_ws, size_t ws_size,
                              hipStream_t stream) {
  (void)in_sizes; (void)n_in; (void)out_size; (void)ws_size;
  const float* hidden = (const float*)d_in[0];
  const float* attn_w = (const float*)d_in[1];
  const float* attn_b = (const float*)d_in[2];
  const float* proj_w = (const float*)d_in[3];
  const float* proj_b = (const float*)d_in[4];
  ConvW cw;
  for (int i = 0; i < 9; i++) {
    cw.w[i] = (const float*)d_in[5 + 2 * i];
    cw.b[i] = (const float*)d_in[6 + 2 * i];
  }

  uint8_t* ws = (uint8_t*)d_ws;
  u16* h_bf   = (u16*)(ws + 0);          //  8,388,608 B
  u16* wqkvT  = (u16*)(ws + 8388608);    //  6,291,456 B
  u16* qkvpre = (u16*)(ws + 14680064);   // 25,165,824 B  [3][2][16][2048][64]
  u16* qpost  = (u16*)(ws + 39845888);   //  8,388,608 B  [2][16][2048][64]
  u16* kpost  = (u16*)(ws + 48234496);   //  8,388,608 B
  u16* vpostT = (u16*)(ws + 56623104);   //  8,388,608 B  [2][16][64][2048]
  u16* attno  = (u16*)(ws + 65011712);   //  8,388,608 B  [2][2048][1024]
  u16* wprojT = (u16*)(ws + 73400320);   //  2,097,152 B
  f2*  ml     = (f2*) (ws + 75497472);   //  2,359,296 B  [2304][128] (m,l)
  u16* Opart  = (u16*)(ws + 0);          // 37,748,736 B  overlay on prologue bufs

  cvt_f32_bf16<<<4096, 256, 0, stream>>>(hidden, h_bf, 4194304);
  transpose_cvt<<<dim3(96, 32), dim3(32, 8), 0, stream>>>(attn_w, wqkvT, 1024, 3072);
  transpose_cvt<<<dim3(32, 32), dim3(32, 8), 0, stream>>>(proj_w, wprojT, 1024, 1024);
  gemm_bt<0, 128, 6><<<768, 256, 0, stream>>>(h_bf, wqkvT, attn_b, (void*)qkvpre, 4096, 3072, 1024);
  conv_mix<<<dim3(16, 16, 6), 256, 0, stream>>>(qkvpre, cw, qpost, kpost, vpostT);
  attn_fwd<<<dim3(2304), 256, 0, stream>>>(qpost, kpost, vpostT, attno, Opart, ml);
  attn_reduce<<<dim3(14, 32), 256, 0, stream>>>(Opart, ml, attno);
  gemm_bt<1, 64, 8><<<512, 256, 0, stream>>>(attno, wprojT, proj_b, d_out, 4096, 1024, 1024);
}

// Round 9
// 256.679 us; speedup vs baseline: 1.2079x; 1.0157x over previous
//
#include <hip/hip_runtime.h>
#include <stdint.h>
#include <math.h>

typedef unsigned short u16;
typedef __attribute__((ext_vector_type(8))) short short8;
typedef __attribute__((ext_vector_type(4))) float floatx4;

#define DEV static __device__ __forceinline__

struct alignas(8) us4 { u16 x, y, z, w; };
struct alignas(16) us8 { u16 v[8]; };
struct alignas(16) f4 { float x, y, z, w; };
struct alignas(8) f2 { float x, y; };
struct alignas(8) u32x2 { uint32_t x, y; };

DEV u16 f2bf(float f) {
  uint32_t u = __float_as_uint(f);
  u += 0x7fffu + ((u >> 16) & 1u);
  return (u16)(u >> 16);
}
DEV float bf2f(u16 h) { return __uint_as_float(((uint32_t)h) << 16); }

DEV uint32_t pkbf(float a, float b) {
#if __has_builtin(__builtin_amdgcn_cvt_pk_bf16_f32)
  typedef __attribute__((ext_vector_type(2))) __bf16 bf2_t;
  bf2_t v = __builtin_amdgcn_cvt_pk_bf16_f32(a, b);
  uint32_t r; __builtin_memcpy(&r, &v, 4); return r;
#else
  return (uint32_t)f2bf(a) | ((uint32_t)f2bf(b) << 16);
#endif
}

DEV float fexp2(float x) {
#if __has_builtin(__builtin_amdgcn_exp2f)
  return __builtin_amdgcn_exp2f(x);
#else
  return exp2f(x);
#endif
}

DEV void load_lds16(const void* g, void* l) {
  __builtin_amdgcn_global_load_lds((const __attribute__((address_space(1))) void*)g,
                                   (__attribute__((address_space(3))) void*)l, 16, 0, 0);
}

// ---------------- elementwise fp32 -> bf16 ----------------
__global__ void cvt_f32_bf16(const float* __restrict__ in, u16* __restrict__ out, int n) {
  int i = (blockIdx.x * blockDim.x + threadIdx.x) * 4;
  if (i < n) {
    f4 v = *(const f4*)(in + i);
    us4 o; o.x = f2bf(v.x); o.y = f2bf(v.y); o.z = f2bf(v.z); o.w = f2bf(v.w);
    *(us4*)(out + i) = o;
  }
}

// ---------------- transpose + convert: W[K][N] fp32 -> WT[N][K] bf16 ----------------
__global__ void transpose_cvt(const float* __restrict__ in, u16* __restrict__ out, int K, int N) {
  __shared__ float tile[32][33];
  const int n0 = blockIdx.x * 32, k0 = blockIdx.y * 32;
  const int tx = threadIdx.x, ty = threadIdx.y;
  for (int i = ty; i < 32; i += 8)
    tile[i][tx] = in[(size_t)(k0 + i) * N + n0 + tx];
  __syncthreads();
  for (int i = ty; i < 32; i += 8)
    out[(size_t)(n0 + i) * K + k0 + tx] = f2bf(tile[tx][i]);
}

// ---------------- bf16 GEMM, C = A[M,K] * Bt[N,K]^T + bias ----------------
template <int EPI, int BN, int NGRP>
__global__ __launch_bounds__(256) void gemm_bt(const u16* __restrict__ A,
                                               const u16* __restrict__ Bt,
                                               const float* __restrict__ bias,
                                               void* __restrict__ outp,
                                               int M, int N, int K) {
  constexpr int NT = BN / 32;
  __shared__ u16 lA[128 * 64];
  __shared__ u16 lB[BN * 64];
  const int t = threadIdx.x;
  const int w = t >> 6, lane = t & 63;
  const int quad = lane >> 4, l15 = lane & 15;
  const int wm = w >> 1, wn = w & 1;
  const int wn_off = wn * (BN / 2);

  const int bid = blockIdx.x;
  const int gsz = 32 * NGRP;
  const int grp = bid / gsz;
  const int r = bid - grp * gsz;
  const int m0 = (r & 31) * 128;
  const int n0 = (grp * NGRP + (r >> 5)) * BN;

  floatx4 acc[4][NT] = {};

  const int srow = t >> 3;
  const int scol = (((t & 7) ^ (srow & 7)) << 3);
  const u16* gA = A + (size_t)(m0 + srow) * K + scol;
  const u16* gB = Bt + (size_t)(n0 + srow) * K + scol;
  u16* sA = lA + t * 8;
  u16* sB = lB + t * 8;
  const size_t rstep = (size_t)32 * K;

  for (int k0 = 0; k0 < K; k0 += 64) {
#pragma unroll
    for (int c = 0; c < 4; c++) load_lds16(gA + c * rstep, sA + c * 2048);
#pragma unroll
    for (int c = 0; c < BN / 32; c++) load_lds16(gB + c * rstep, sB + c * 2048);
    gA += 64; gB += 64;
    __syncthreads();
#pragma unroll
    for (int kc = 0; kc < 2; kc++) {
      short8 af[4], bfr[NT];
#pragma unroll
      for (int mt = 0; mt < 4; mt++)
        af[mt] = *(const short8*)&lA[(wm * 64 + mt * 16 + l15) * 64 + (((kc * 4 + quad) ^ (l15 & 7)) << 3)];
#pragma unroll
      for (int nt = 0; nt < NT; nt++)
        bfr[nt] = *(const short8*)&lB[(wn_off + nt * 16 + l15) * 64 + (((kc * 4 + quad) ^ (l15 & 7)) << 3)];
#pragma unroll
      for (int mt = 0; mt < 4; mt++)
#pragma unroll
        for (int nt = 0; nt < NT; nt++)
          acc[mt][nt] = __builtin_amdgcn_mfma_f32_16x16x32_bf16(bfr[nt], af[mt], acc[mt][nt], 0, 0, 0);
    }
    __syncthreads();
  }

  if (EPI == 0) {
    u16* outq = (u16*)outp;
#pragma unroll
    for (int nt = 0; nt < NT; nt++) {
      const int nb = n0 + wn_off + nt * 16 + quad * 4;
      const f4 bn4 = *(const f4*)&bias[nb];
      const int tensor = nb >> 10, e = nb & 1023;
      const int h = e >> 6, d = e & 63;
      const size_t abase = (size_t)tensor * 4194304 + (size_t)h * 131072 + d;
#pragma unroll
      for (int mt = 0; mt < 4; mt++) {
        const int rr = m0 + wm * 64 + mt * 16 + l15;
        const int b = rr >> 11, s = rr & 2047;
        u32x2 o;
        o.x = pkbf(acc[mt][nt][0] + bn4.x, acc[mt][nt][1] + bn4.y);
        o.y = pkbf(acc[mt][nt][2] + bn4.z, acc[mt][nt][3] + bn4.w);
        *(u32x2*)&outq[abase + (size_t)b * 2097152 + (size_t)s * 64] = o;
      }
    }
  } else {
    float* outf = (float*)outp;
#pragma unroll
    for (int nt = 0; nt < NT; nt++) {
      const int nb = n0 + wn_off + nt * 16 + quad * 4;
      const f4 bn4 = *(const f4*)&bias[nb];
#pragma unroll
      for (int mt = 0; mt < 4; mt++) {
        const int rr = m0 + wm * 64 + mt * 16 + l15;
        f4 o;
        o.x = acc[mt][nt][0] + bn4.x;
        o.y = acc[mt][nt][1] + bn4.y;
        o.z = acc[mt][nt][2] + bn4.z;
        o.w = acc[mt][nt][3] + bn4.w;
        *(f4*)&outf[(size_t)rr * N + nb] = o;
      }
    }
  }
}

// ---------------- causal depthwise conv / head-mix (register sliding window) ----------------
struct ConvW { const float* w[9]; const float* b[9]; };

template <int K>
DEV void conv_run(const u16* xt, int sl0, int d, const float* wp, const float* bp,
                  float qscale, float* out32) {
  float wr[K];
#pragma unroll
  for (int j = 0; j < K; j++) wr[j] = wp[d * K + j];
  const float br = bp[d];
  float win[K];
#pragma unroll
  for (int m = 1; m < K; m++) win[m] = bf2f(xt[(sl0 + 6 - K + m) * 68 + d]);
#pragma unroll
  for (int i = 0; i < 32; i++) {
#pragma unroll
    for (int m = 0; m < K - 1; m++) win[m] = win[m + 1];
    win[K - 1] = bf2f(xt[(sl0 + 6 + i) * 68 + d]);
    float val = br;
#pragma unroll
    for (int j = 0; j < K; j++) val += wr[j] * win[j];
    out32[i] = val * qscale;
  }
}

__global__ __launch_bounds__(256) void conv_mix(const u16* __restrict__ qkv, ConvW cw,
                                                u16* __restrict__ qpost,
                                                u16* __restrict__ kpost,
                                                u16* __restrict__ vpostT) {
  __shared__ u16 xt[134 * 68];   // [s-halo 134][d 64 +4 pad]
  __shared__ u16 yt[64 * 136];   // V transpose staging [d][sl 128 +8 pad]
  const int t = threadIdx.x;
  const int s0 = blockIdx.x * 128;
  const int h = blockIdx.y;
  const int tz = blockIdx.z;
  const int tensor = tz >> 1, b = tz & 1;
  const u16* src = qkv + (((size_t)tensor * 2 + b) * 16 + h) * 131072;

  for (int idx = t; idx < 134 * 16; idx += 256) {
    const int row = idx >> 4, c4 = (idx & 15) << 2;
    const int s = s0 - 6 + row;
    us4 v = {0, 0, 0, 0};
    if (s >= 0) v = *(const us4*)&src[(size_t)s * 64 + c4];
    *(us4*)&xt[row * 68 + c4] = v;
  }
  __syncthreads();

  const int group = h >> 2;
  const float* wp = (group > 0) ? cw.w[tensor * 3 + group - 1] : nullptr;
  const float* bp = (group > 0) ? cw.b[tensor * 3 + group - 1] : nullptr;
  const float qscale = (tensor == 0) ? 0.18033688f : 1.0f;

  const int d = t & 63;
  const int sl0 = (t >> 6) * 32;

  float out32[32];
  if (group == 0) {
#pragma unroll
    for (int i = 0; i < 32; i++)
      out32[i] = bf2f(xt[(sl0 + 6 + i) * 68 + d]) * qscale;
  } else if (group == 1) {
    conv_run<3>(xt, sl0, d, wp, bp, qscale, out32);
  } else if (group == 2) {
    conv_run<5>(xt, sl0, d, wp, bp, qscale, out32);
  } else {
    conv_run<7>(xt, sl0, d, wp, bp, qscale, out32);
  }

  if (tensor < 2) {
    u16* outp = (tensor == 0) ? qpost : kpost;
    const size_t ob = (((size_t)b * 16 + h) * 2048 + s0) * 64;
#pragma unroll
    for (int i = 0; i < 32; i++)
      outp[ob + (size_t)(sl0 + i) * 64 + d] = f2bf(out32[i]);
  } else {
#pragma unroll
    for (int i = 0; i < 32; i++)
      yt[d * 136 + sl0 + i] = f2bf(out32[i]);
    __syncthreads();
    const size_t ob = ((size_t)b * 16 + h) * 64;
    const int sl = (t & 15) * 8;
#pragma unroll
    for (int pass = 0; pass < 4; pass++) {
      const int dd = (t >> 4) + pass * 16;
      us8 vv = *(const us8*)&yt[dd * 136 + sl];
      *(us8*)&vpostT[(ob + dd) * 2048 + s0 + sl] = vv;
    }
  }
}

// ---------------- split-kv causal flash attention ----------------
// R7-proven structure; lP halved to [32 q][64 kv] per wave via two-pass PV over
// kv-halves (P packed in regs after softmax, then per-half LDS write->read->MFMA).
// Slot/read swizzles identical to the R2-proven 64-kv lP kernel.
// LDS: lK 16K + lV 16K + lP 16K = 48 KB -> 3 blocks/CU.
__global__ __launch_bounds__(256) void attn_fwd(const u16* __restrict__ Q,
                                                const u16* __restrict__ Kp,
                                                const u16* __restrict__ Vt,
                                                u16* __restrict__ Out,
                                                u16* __restrict__ Opart,
                                                f2* __restrict__ ml) {
  __shared__ u16 lK[128 * 64];       // [kv][d]
  __shared__ u16 lV[64 * 128];       // [d][kv]
  __shared__ u16 lP[4][32 * 64];     // per wave: [q_local][kv half]
  const int t = threadIdx.x;
  const int w = t >> 6, lane = t & 63;
  const int quad = lane >> 4, l15 = lane & 15;
  const int e7 = l15 & 7;

  const int lin = blockIdx.x;
  const int xcd = lin & 7;
  const int idx = lin >> 3;          // 0..287
  const int grp = idx / 72;          // 0..3
  const int u = idx - grp * 72;      // 0..71
  const int bh = grp * 8 + xcd;
  int p = (int)(0.5f * (sqrtf(4.0f * (float)u + 1.0f) - 1.0f));
  if ((p + 1) * (p + 2) <= u) p++;
  if (p * (p + 1) > u) p--;
  const int v = u - p * (p + 1);
  const int qi = 2 * p + (v >= p + 1 ? 1 : 0);
  const int slab = v - (v >= p + 1 ? p + 1 : 0);
  const int ns = (qi + 2) >> 1;
  const int jbeg = slab * 2;
  const int jend = min(jbeg + 2, qi + 1);

  const int b = bh >> 4, h = bh & 15;
  const size_t qkbase = (size_t)bh * 131072;
  const int qblk = qi * 128 + w * 32;

  short8 qf[2][2];
#pragma unroll
  for (int qt = 0; qt < 2; qt++)
#pragma unroll
    for (int kc = 0; kc < 2; kc++)
      qf[qt][kc] = *(const short8*)&Q[qkbase + (size_t)(qblk + qt * 16 + l15) * 64 + kc * 32 + quad * 8];

  float mst[2] = {-3.0e38f, -3.0e38f};
  float lst[2] = {0.0f, 0.0f};
  floatx4 accO[4][2] = {};

  const int krow = t >> 3;
  const int kcol = (((t & 7) ^ (krow & 7)) << 3);
  const u16* gK = Kp + qkbase + (size_t)krow * 64 + kcol;
  const int vrow = t >> 4;
  const int vcol = (((t & 15) ^ vrow) << 3);
  const u16* gV = Vt + qkbase + (size_t)vrow * 2048 + vcol;
  u16* sK = lK + t * 8;
  u16* sV = lV + t * 8;
  u16* myP = lP[w];

  for (int j = jbeg; j < jend; j++) {
    const int j0 = j * 128;
#pragma unroll
    for (int c = 0; c < 4; c++) {
      load_lds16(gK + (size_t)(j0 + c * 32) * 64, sK + c * 2048);
      load_lds16(gV + j0 + c * 16 * 2048, sV + c * 2048);
    }
    __syncthreads();

    floatx4 accS[8][2] = {};
#pragma unroll
    for (int kvt = 0; kvt < 8; kvt++) {
#pragma unroll
      for (int kc = 0; kc < 2; kc++) {
        const short8 a = *(const short8*)&lK[(kvt * 16 + l15) * 64 + (((kc * 4 + quad) ^ e7) << 3)];
#pragma unroll
        for (int qt = 0; qt < 2; qt++)
          accS[kvt][qt] = __builtin_amdgcn_mfma_f32_16x16x32_bf16(a, qf[qt][kc], accS[kvt][qt], 0, 0, 0);
      }
    }

    if (j == qi) {
#pragma unroll
      for (int qt = 0; qt < 2; qt++) {
        const int q = qblk + qt * 16 + l15;
#pragma unroll
        for (int kvt = 0; kvt < 8; kvt++)
#pragma unroll
          for (int r = 0; r < 4; r++) {
            const int kv = j0 + kvt * 16 + quad * 4 + r;
            if (kv > q) accS[kvt][qt][r] = -3.0e38f;
          }
      }
    }

    // softmax; P packed into registers (verified-safe piece of R8)
    uint32_t pk01[2][8], pk23[2][8];
    float alpha[2];
#pragma unroll
    for (int qt = 0; qt < 2; qt++) {
      float tm = -3.0e38f;
#pragma unroll
      for (int kvt = 0; kvt < 8; kvt++)
#pragma unroll
        for (int r = 0; r < 4; r++)
          tm = fmaxf(tm, accS[kvt][qt][r]);
      tm = fmaxf(tm, __shfl_xor(tm, 16));
      tm = fmaxf(tm, __shfl_xor(tm, 32));
      const float mnew = fmaxf(mst[qt], tm);
      alpha[qt] = fexp2(mst[qt] - mnew);
      mst[qt] = mnew;
      float ts = 0.0f;
#pragma unroll
      for (int kvt = 0; kvt < 8; kvt++) {
        const float p0 = fexp2(accS[kvt][qt][0] - mnew);
        const float p1 = fexp2(accS[kvt][qt][1] - mnew);
        const float p2 = fexp2(accS[kvt][qt][2] - mnew);
        const float p3 = fexp2(accS[kvt][qt][3] - mnew);
        ts += (p0 + p1) + (p2 + p3);
        pk01[qt][kvt] = pkbf(p0, p1);
        pk23[qt][kvt] = pkbf(p2, p3);
      }
      ts += __shfl_xor(ts, 16);
      ts += __shfl_xor(ts, 32);
      lst[qt] = lst[qt] * alpha[qt] + ts;
    }

#pragma unroll
    for (int dt = 0; dt < 4; dt++)
#pragma unroll
      for (int qt = 0; qt < 2; qt++)
#pragma unroll
        for (int r = 0; r < 4; r++)
          accO[dt][qt][r] *= alpha[qt];

    // PV in two kv-half passes through the halved lP
#pragma unroll
    for (int kvh = 0; kvh < 2; kvh++) {
#pragma unroll
      for (int qt = 0; qt < 2; qt++) {
        const int prow = (qt * 16 + l15) * 64;
#pragma unroll
        for (int kt = 0; kt < 4; kt++) {
          const int kvt = kvh * 4 + kt;
          const int slot = (kt * 2 + (quad >> 1)) ^ e7;
          u32x2 pk; pk.x = pk01[qt][kvt]; pk.y = pk23[qt][kvt];
          *(u32x2*)&myP[prow + slot * 8 + (quad & 1) * 4] = pk;
        }
      }
      asm volatile("s_waitcnt lgkmcnt(0)" ::: "memory");  // own-wave P writes visible
#pragma unroll
      for (int kk = 0; kk < 2; kk++) {
        const int kvc = kvh * 2 + kk;
        short8 pf[2];
#pragma unroll
        for (int qt = 0; qt < 2; qt++)
          pf[qt] = *(const short8*)&myP[(qt * 16 + l15) * 64 + (((kk * 4 + quad) ^ e7) << 3)];
#pragma unroll
        for (int dt = 0; dt < 4; dt++) {
          const short8 vf = *(const short8*)&lV[(dt * 16 + l15) * 128 + (((kvc * 4 + quad) ^ l15) << 3)];
#pragma unroll
          for (int qt = 0; qt < 2; qt++)
            accO[dt][qt] = __builtin_amdgcn_mfma_f32_16x16x32_bf16(vf, pf[qt], accO[dt][qt], 0, 0, 0);
        }
      }
    }
    __syncthreads();
  }

  if (ns == 1) {
#pragma unroll
    for (int qt = 0; qt < 2; qt++) {
      const float inv = 1.0f / lst[qt];
      const int q = qblk + qt * 16 + l15;
#pragma unroll
      for (int dt = 0; dt < 4; dt++) {
        u32x2 o;
        o.x = pkbf(accO[dt][qt][0] * inv, accO[dt][qt][1] * inv);
        o.y = pkbf(accO[dt][qt][2] * inv, accO[dt][qt][3] * inv);
        *(u32x2*)&Out[((size_t)b * 2048 + q) * 1024 + h * 64 + dt * 16 + quad * 4] = o;
      }
    }
  } else {
    const int slot = bh * 72 + u;
    u16* op = Opart + (size_t)slot * 8192;
#pragma unroll
    for (int qt = 0; qt < 2; qt++) {
      const int ql = w * 32 + qt * 16 + l15;
#pragma unroll
      for (int dt = 0; dt < 4; dt++) {
        u32x2 o;
        o.x = pkbf(accO[dt][qt][0], accO[dt][qt][1]);
        o.y = pkbf(accO[dt][qt][2], accO[dt][qt][3]);
        *(u32x2*)&op[(size_t)ql * 64 + dt * 16 + quad * 4] = o;
      }
      if (quad == 0) {
        f2 v2; v2.x = mst[qt]; v2.y = lst[qt];
        ml[slot * 128 + ql] = v2;
      }
    }
  }
}

// ---------------- split-kv reduction (exp2 domain) ----------------
__global__ __launch_bounds__(256) void attn_reduce(const u16* __restrict__ Opart,
                                                   const f2* __restrict__ ml,
                                                   u16* __restrict__ Out) {
  const int qi = blockIdx.x + 2;
  const int bh = blockIdx.y;
  const int b = bh >> 4, h = bh & 15;
  const int p = qi >> 1;
  const int base = bh * 72 + p * (p + 1) + (qi & 1) * (p + 1);
  const int ns = (qi + 2) >> 1;
  const int t = threadIdx.x;
  const int q = t >> 1, dh = (t & 1) * 32;

  float m[8], l[8], wgt[8];
  float mmax = -3.0e38f;
  for (int s = 0; s < ns; s++) {
    f2 v = ml[(base + s) * 128 + q];
    m[s] = v.x; l[s] = v.y;
    mmax = fmaxf(mmax, m[s]);
  }
  float lsum = 0.0f;
  for (int s = 0; s < ns; s++) {
    wgt[s] = fexp2(m[s] - mmax);
    lsum += wgt[s] * l[s];
  }
  float acc[32] = {};
  for (int s = 0; s < ns; s++) {
    const u16* src = Opart + ((size_t)(base + s) * 128 + q) * 64 + dh;
    const float ws = wgt[s];
#pragma unroll
    for (int i = 0; i < 8; i++) {
      us4 vv = *(const us4*)&src[i * 4];
      acc[i * 4 + 0] += ws * bf2f(vv.x);
      acc[i * 4 + 1] += ws * bf2f(vv.y);
      acc[i * 4 + 2] += ws * bf2f(vv.z);
      acc[i * 4 + 3] += ws * bf2f(vv.w);
    }
  }
  const float inv = 1.0f / lsum;
  u16* dst = Out + ((size_t)b * 2048 + qi * 128 + q) * 1024 + h * 64 + dh;
#pragma unroll
  for (int i = 0; i < 8; i++) {
    u32x2 o;
    o.x = pkbf(acc[i * 4 + 0] * inv, acc[i * 4 + 1] * inv);
    o.y = pkbf(acc[i * 4 + 2] * inv, acc[i * 4 + 3] * inv);
    *(u32x2*)&dst[i * 4] = o;
  }
}

// ---------------- launcher ----------------
extern "C" void kernel_launch(void* const* d_in, const int* in_sizes, int n_in,
                              void* d_out, int out_size, void* d_ws, size_t ws_size,
                              hipStream_t stream) {
  (void)in_sizes; (void)n_in; (void)out_size; (void)ws_size;
  const float* hidden = (const float*)d_in[0];
  const float* attn_w = (const float*)d_in[1];
  const float* attn_b = (const float*)d_in[2];
  const float* proj_w = (const float*)d_in[3];
  const float* proj_b = (const float*)d_in[4];
  ConvW cw;
  for (int i = 0; i < 9; i++) {
    cw.w[i] = (const float*)d_in[5 + 2 * i];
    cw.b[i] = (const float*)d_in[6 + 2 * i];
  }

  uint8_t* ws = (uint8_t*)d_ws;
  u16* h_bf   = (u16*)(ws + 0);          //  8,388,608 B
  u16* wqkvT  = (u16*)(ws + 8388608);    //  6,291,456 B
  u16* qkvpre = (u16*)(ws + 14680064);   // 25,165,824 B  [3][2][16][2048][64]
  u16* qpost  = (u16*)(ws + 39845888);   //  8,388,608 B  [2][16][2048][64]
  u16* kpost  = (u16*)(ws + 48234496);   //  8,388,608 B
  u16* vpostT = (u16*)(ws + 56623104);   //  8,388,608 B  [2][16][64][2048]
  u16* attno  = (u16*)(ws + 65011712);   //  8,388,608 B  [2][2048][1024]
  u16* wprojT = (u16*)(ws + 73400320);   //  2,097,152 B
  f2*  ml     = (f2*) (ws + 75497472);   //  2,359,296 B  [2304][128] (m,l)
  u16* Opart  = (u16*)(ws + 0);          // 37,748,736 B  overlay on prologue bufs

  cvt_f32_bf16<<<4096, 256, 0, stream>>>(hidden, h_bf, 4194304);
  transpose_cvt<<<dim3(96, 32), dim3(32, 8), 0, stream>>>(attn_w, wqkvT, 1024, 3072);
  transpose_cvt<<<dim3(32, 32), dim3(32, 8), 0, stream>>>(proj_w, wprojT, 1024, 1024);
  gemm_bt<0, 128, 6><<<768, 256, 0, stream>>>(h_bf, wqkvT, attn_b, (void*)qkvpre, 4096, 3072, 1024);
  conv_mix<<<dim3(16, 16, 6), 256, 0, stream>>>(qkvpre, cw, qpost, kpost, vpostT);
  attn_fwd<<<dim3(2304), 256, 0, stream>>>(qpost, kpost, vpostT, attno, Opart, ml);
  attn_reduce<<<dim3(14, 32), 256, 0, stream>>>(Opart, ml, attno);
  gemm_bt<1, 64, 8><<<512, 256, 0, stream>>>(attno, wprojT, proj_b, d_out, 4096, 1024, 1024);
}

// Round 10
// 254.629 us; speedup vs baseline: 1.2176x; 1.0081x over previous
//
#include <hip/hip_runtime.h>
#include <stdint.h>
#include <math.h>

typedef unsigned short u16;
typedef __attribute__((ext_vector_type(8))) short short8;
typedef __attribute__((ext_vector_type(4))) float floatx4;

#define DEV static __device__ __forceinline__

struct alignas(8) us4 { u16 x, y, z, w; };
struct alignas(16) us8 { u16 v[8]; };
struct alignas(16) f4 { float x, y, z, w; };
struct alignas(8) f2 { float x, y; };
struct alignas(8) u32x2 { uint32_t x, y; };

DEV u16 f2bf(float f) {
  uint32_t u = __float_as_uint(f);
  u += 0x7fffu + ((u >> 16) & 1u);
  return (u16)(u >> 16);
}
DEV float bf2f(u16 h) { return __uint_as_float(((uint32_t)h) << 16); }

DEV uint32_t pkbf(float a, float b) {
#if __has_builtin(__builtin_amdgcn_cvt_pk_bf16_f32)
  typedef __attribute__((ext_vector_type(2))) __bf16 bf2_t;
  bf2_t v = __builtin_amdgcn_cvt_pk_bf16_f32(a, b);
  uint32_t r; __builtin_memcpy(&r, &v, 4); return r;
#else
  return (uint32_t)f2bf(a) | ((uint32_t)f2bf(b) << 16);
#endif
}

DEV float fexp2(float x) {
#if __has_builtin(__builtin_amdgcn_exp2f)
  return __builtin_amdgcn_exp2f(x);
#else
  return exp2f(x);
#endif
}

DEV void load_lds16(const void* g, void* l) {
  __builtin_amdgcn_global_load_lds((const __attribute__((address_space(1))) void*)g,
                                   (__attribute__((address_space(3))) void*)l, 16, 0, 0);
}

// ---------------- fused prologue: cvt hidden + transpose both weights ----------------
__global__ __launch_bounds__(256) void prep_fused(const float* __restrict__ hidden, u16* __restrict__ h_bf,
                                                  const float* __restrict__ attn_w, u16* __restrict__ wqkvT,
                                                  const float* __restrict__ proj_w, u16* __restrict__ wprojT) {
  __shared__ float tile[32][33];
  const int bx = blockIdx.x;
  const int t = threadIdx.x;
  if (bx < 4096) {
    const int i = (bx * 256 + t) * 4;
    f4 v = *(const f4*)(hidden + i);
    us4 o; o.x = f2bf(v.x); o.y = f2bf(v.y); o.z = f2bf(v.z); o.w = f2bf(v.w);
    *(us4*)(h_bf + i) = o;
    return;
  }
  const float* in; u16* out; int K, N, n0, k0;
  if (bx < 7168) {
    const int bid = bx - 4096;  // 96 x 32
    in = attn_w; out = wqkvT; K = 1024; N = 3072;
    n0 = (bid % 96) * 32; k0 = (bid / 96) * 32;
  } else {
    const int bid = bx - 7168;  // 32 x 32
    in = proj_w; out = wprojT; K = 1024; N = 1024;
    n0 = (bid & 31) * 32; k0 = (bid >> 5) * 32;
  }
  const int tx = t & 31, ty = t >> 5;
  for (int i = ty; i < 32; i += 8)
    tile[i][tx] = in[(size_t)(k0 + i) * N + n0 + tx];
  __syncthreads();
  for (int i = ty; i < 32; i += 8)
    out[(size_t)(n0 + i) * K + k0 + tx] = f2bf(tile[tx][i]);
}

// ---------------- bf16 GEMM, C = A[M,K] * Bt[N,K]^T + bias ----------------
template <int EPI, int BN, int NGRP>
__global__ __launch_bounds__(256) void gemm_bt(const u16* __restrict__ A,
                                               const u16* __restrict__ Bt,
                                               const float* __restrict__ bias,
                                               void* __restrict__ outp,
                                               int M, int N, int K) {
  constexpr int NT = BN / 32;
  __shared__ u16 lA[128 * 64];
  __shared__ u16 lB[BN * 64];
  const int t = threadIdx.x;
  const int w = t >> 6, lane = t & 63;
  const int quad = lane >> 4, l15 = lane & 15;
  const int wm = w >> 1, wn = w & 1;
  const int wn_off = wn * (BN / 2);

  const int bid = blockIdx.x;
  const int gsz = 32 * NGRP;
  const int grp = bid / gsz;
  const int r = bid - grp * gsz;
  const int m0 = (r & 31) * 128;
  const int n0 = (grp * NGRP + (r >> 5)) * BN;

  floatx4 acc[4][NT] = {};

  const int srow = t >> 3;
  const int scol = (((t & 7) ^ (srow & 7)) << 3);
  const u16* gA = A + (size_t)(m0 + srow) * K + scol;
  const u16* gB = Bt + (size_t)(n0 + srow) * K + scol;
  u16* sA = lA + t * 8;
  u16* sB = lB + t * 8;
  const size_t rstep = (size_t)32 * K;

  for (int k0 = 0; k0 < K; k0 += 64) {
#pragma unroll
    for (int c = 0; c < 4; c++) load_lds16(gA + c * rstep, sA + c * 2048);
#pragma unroll
    for (int c = 0; c < BN / 32; c++) load_lds16(gB + c * rstep, sB + c * 2048);
    gA += 64; gB += 64;
    __syncthreads();
#pragma unroll
    for (int kc = 0; kc < 2; kc++) {
      short8 af[4], bfr[NT];
#pragma unroll
      for (int mt = 0; mt < 4; mt++)
        af[mt] = *(const short8*)&lA[(wm * 64 + mt * 16 + l15) * 64 + (((kc * 4 + quad) ^ (l15 & 7)) << 3)];
#pragma unroll
      for (int nt = 0; nt < NT; nt++)
        bfr[nt] = *(const short8*)&lB[(wn_off + nt * 16 + l15) * 64 + (((kc * 4 + quad) ^ (l15 & 7)) << 3)];
#pragma unroll
      for (int mt = 0; mt < 4; mt++)
#pragma unroll
        for (int nt = 0; nt < NT; nt++)
          acc[mt][nt] = __builtin_amdgcn_mfma_f32_16x16x32_bf16(bfr[nt], af[mt], acc[mt][nt], 0, 0, 0);
    }
    __syncthreads();
  }

  if (EPI == 0) {
    u16* outq = (u16*)outp;
#pragma unroll
    for (int nt = 0; nt < NT; nt++) {
      const int nb = n0 + wn_off + nt * 16 + quad * 4;
      const f4 bn4 = *(const f4*)&bias[nb];
      const int tensor = nb >> 10, e = nb & 1023;
      const int h = e >> 6, d = e & 63;
      const size_t abase = (size_t)tensor * 4194304 + (size_t)h * 131072 + d;
#pragma unroll
      for (int mt = 0; mt < 4; mt++) {
        const int rr = m0 + wm * 64 + mt * 16 + l15;
        const int b = rr >> 11, s = rr & 2047;
        u32x2 o;
        o.x = pkbf(acc[mt][nt][0] + bn4.x, acc[mt][nt][1] + bn4.y);
        o.y = pkbf(acc[mt][nt][2] + bn4.z, acc[mt][nt][3] + bn4.w);
        *(u32x2*)&outq[abase + (size_t)b * 2097152 + (size_t)s * 64] = o;
      }
    }
  } else {
    float* outf = (float*)outp;
#pragma unroll
    for (int nt = 0; nt < NT; nt++) {
      const int nb = n0 + wn_off + nt * 16 + quad * 4;
      const f4 bn4 = *(const f4*)&bias[nb];
#pragma unroll
      for (int mt = 0; mt < 4; mt++) {
        const int rr = m0 + wm * 64 + mt * 16 + l15;
        f4 o;
        o.x = acc[mt][nt][0] + bn4.x;
        o.y = acc[mt][nt][1] + bn4.y;
        o.z = acc[mt][nt][2] + bn4.z;
        o.w = acc[mt][nt][3] + bn4.w;
        *(f4*)&outf[(size_t)rr * N + nb] = o;
      }
    }
  }
}

// ---------------- causal depthwise conv / head-mix (register sliding window) ----------------
struct ConvW { const float* w[9]; const float* b[9]; };

template <int K>
DEV void conv_run(const u16* xt, int sl0, int d, const float* wp, const float* bp,
                  float qscale, float* out32) {
  float wr[K];
#pragma unroll
  for (int j = 0; j < K; j++) wr[j] = wp[d * K + j];
  const float br = bp[d];
  float win[K];
#pragma unroll
  for (int m = 1; m < K; m++) win[m] = bf2f(xt[(sl0 + 6 - K + m) * 68 + d]);
#pragma unroll
  for (int i = 0; i < 32; i++) {
#pragma unroll
    for (int m = 0; m < K - 1; m++) win[m] = win[m + 1];
    win[K - 1] = bf2f(xt[(sl0 + 6 + i) * 68 + d]);
    float val = br;
#pragma unroll
    for (int j = 0; j < K; j++) val += wr[j] * win[j];
    out32[i] = val * qscale;
  }
}

__global__ __launch_bounds__(256) void conv_mix(const u16* __restrict__ qkv, ConvW cw,
                                                u16* __restrict__ qpost,
                                                u16* __restrict__ kpost,
                                                u16* __restrict__ vpostT) {
  __shared__ u16 xt[134 * 68];
  __shared__ u16 yt[64 * 136];
  const int t = threadIdx.x;
  const int s0 = blockIdx.x * 128;
  const int h = blockIdx.y;
  const int tz = blockIdx.z;
  const int tensor = tz >> 1, b = tz & 1;
  const u16* src = qkv + (((size_t)tensor * 2 + b) * 16 + h) * 131072;

  for (int idx = t; idx < 134 * 16; idx += 256) {
    const int row = idx >> 4, c4 = (idx & 15) << 2;
    const int s = s0 - 6 + row;
    us4 v = {0, 0, 0, 0};
    if (s >= 0) v = *(const us4*)&src[(size_t)s * 64 + c4];
    *(us4*)&xt[row * 68 + c4] = v;
  }
  __syncthreads();

  const int group = h >> 2;
  const float* wp = (group > 0) ? cw.w[tensor * 3 + group - 1] : nullptr;
  const float* bp = (group > 0) ? cw.b[tensor * 3 + group - 1] : nullptr;
  const float qscale = (tensor == 0) ? 0.18033688f : 1.0f;

  const int d = t & 63;
  const int sl0 = (t >> 6) * 32;

  float out32[32];
  if (group == 0) {
#pragma unroll
    for (int i = 0; i < 32; i++)
      out32[i] = bf2f(xt[(sl0 + 6 + i) * 68 + d]) * qscale;
  } else if (group == 1) {
    conv_run<3>(xt, sl0, d, wp, bp, qscale, out32);
  } else if (group == 2) {
    conv_run<5>(xt, sl0, d, wp, bp, qscale, out32);
  } else {
    conv_run<7>(xt, sl0, d, wp, bp, qscale, out32);
  }

  if (tensor < 2) {
    u16* outp = (tensor == 0) ? qpost : kpost;
    const size_t ob = (((size_t)b * 16 + h) * 2048 + s0) * 64;
#pragma unroll
    for (int i = 0; i < 32; i++)
      outp[ob + (size_t)(sl0 + i) * 64 + d] = f2bf(out32[i]);
  } else {
#pragma unroll
    for (int i = 0; i < 32; i++)
      yt[d * 136 + sl0 + i] = f2bf(out32[i]);
    __syncthreads();
    const size_t ob = ((size_t)b * 16 + h) * 64;
    const int sl = (t & 15) * 8;
#pragma unroll
    for (int pass = 0; pass < 4; pass++) {
      const int dd = (t >> 4) + pass * 16;
      us8 vv = *(const us8*)&yt[dd * 136 + sl];
      *(us8*)&vpostT[(ob + dd) * 2048 + s0 + sl] = vv;
    }
  }
}

// ---------------- split-kv causal flash attention (single-drain blocks) ----------------
// Whole 256-kv slab staged up front into double-width lK/lV: ONE vmcnt drain +
// ONE __syncthreads per block; compute halves run barrier-free (lP is per-wave,
// R9-proven in-order pattern). LDS: 32K lK + 32K lV + 16K lP = 80 KB.
__global__ __launch_bounds__(256) void attn_fwd(const u16* __restrict__ Q,
                                                const u16* __restrict__ Kp,
                                                const u16* __restrict__ Vt,
                                                u16* __restrict__ Out,
                                                u16* __restrict__ Opart,
                                                f2* __restrict__ ml) {
  __shared__ u16 lK[2][128 * 64];    // [half][kv][d]
  __shared__ u16 lV[2][64 * 128];    // [half][d][kv]
  __shared__ u16 lP[4][32 * 64];     // per wave: [q_local][kv half]
  const int t = threadIdx.x;
  const int w = t >> 6, lane = t & 63;
  const int quad = lane >> 4, l15 = lane & 15;
  const int e7 = l15 & 7;

  const int lin = blockIdx.x;
  const int xcd = lin & 7;
  const int idx = lin >> 3;          // 0..287
  const int grp = idx / 72;          // 0..3
  const int u = idx - grp * 72;      // 0..71
  const int bh = grp * 8 + xcd;
  int p = (int)(0.5f * (sqrtf(4.0f * (float)u + 1.0f) - 1.0f));
  if ((p + 1) * (p + 2) <= u) p++;
  if (p * (p + 1) > u) p--;
  const int v = u - p * (p + 1);
  const int qi = 2 * p + (v >= p + 1 ? 1 : 0);
  const int slab = v - (v >= p + 1 ? p + 1 : 0);
  const int ns = (qi + 2) >> 1;
  const int jbeg = slab * 2;
  const int nh = min(2, qi + 1 - jbeg);

  const int b = bh >> 4, h = bh & 15;
  const size_t qkbase = (size_t)bh * 131072;
  const int qblk = qi * 128 + w * 32;

  short8 qf[2][2];
#pragma unroll
  for (int qt = 0; qt < 2; qt++)
#pragma unroll
    for (int kc = 0; kc < 2; kc++)
      qf[qt][kc] = *(const short8*)&Q[qkbase + (size_t)(qblk + qt * 16 + l15) * 64 + kc * 32 + quad * 8];

  float mst[2] = {-3.0e38f, -3.0e38f};
  float lst[2] = {0.0f, 0.0f};
  floatx4 accO[4][2] = {};

  const int krow = t >> 3;
  const int kcol = (((t & 7) ^ (krow & 7)) << 3);
  const u16* gK = Kp + qkbase + (size_t)krow * 64 + kcol;
  const int vrow = t >> 4;
  const int vcol = (((t & 15) ^ vrow) << 3);
  const u16* gV = Vt + qkbase + (size_t)vrow * 2048 + vcol;
  u16* myP = lP[w];

  // stage ALL kv for this block (1 or 2 tiles), then one drain+barrier
  for (int hf = 0; hf < nh; hf++) {
    const int j0 = (jbeg + hf) * 128;
    u16* sK = &lK[hf][0] + t * 8;
    u16* sV = &lV[hf][0] + t * 8;
#pragma unroll
    for (int c = 0; c < 4; c++) {
      load_lds16(gK + (size_t)(j0 + c * 32) * 64, sK + c * 2048);
      load_lds16(gV + j0 + c * 16 * 2048, sV + c * 2048);
    }
  }
  __syncthreads();  // single sync point in the kernel

  for (int hf = 0; hf < nh; hf++) {
    const int j = jbeg + hf;
    const int j0 = j * 128;
    const u16* cK = lK[hf];
    const u16* cV = lV[hf];

    floatx4 accS[8][2] = {};
#pragma unroll
    for (int kvt = 0; kvt < 8; kvt++) {
#pragma unroll
      for (int kc = 0; kc < 2; kc++) {
        const short8 a = *(const short8*)&cK[(kvt * 16 + l15) * 64 + (((kc * 4 + quad) ^ e7) << 3)];
#pragma unroll
        for (int qt = 0; qt < 2; qt++)
          accS[kvt][qt] = __builtin_amdgcn_mfma_f32_16x16x32_bf16(a, qf[qt][kc], accS[kvt][qt], 0, 0, 0);
      }
    }

    if (j == qi) {
#pragma unroll
      for (int qt = 0; qt < 2; qt++) {
        const int q = qblk + qt * 16 + l15;
#pragma unroll
        for (int kvt = 0; kvt < 8; kvt++)
#pragma unroll
          for (int r = 0; r < 4; r++) {
            const int kv = j0 + kvt * 16 + quad * 4 + r;
            if (kv > q) accS[kvt][qt][r] = -3.0e38f;
          }
      }
    }

    uint32_t pk01[2][8], pk23[2][8];
    float alpha[2];
#pragma unroll
    for (int qt = 0; qt < 2; qt++) {
      float tm = -3.0e38f;
#pragma unroll
      for (int kvt = 0; kvt < 8; kvt++)
#pragma unroll
        for (int r = 0; r < 4; r++)
          tm = fmaxf(tm, accS[kvt][qt][r]);
      tm = fmaxf(tm, __shfl_xor(tm, 16));
      tm = fmaxf(tm, __shfl_xor(tm, 32));
      const float mnew = fmaxf(mst[qt], tm);
      alpha[qt] = fexp2(mst[qt] - mnew);
      mst[qt] = mnew;
      float ts = 0.0f;
#pragma unroll
      for (int kvt = 0; kvt < 8; kvt++) {
        const float p0 = fexp2(accS[kvt][qt][0] - mnew);
        const float p1 = fexp2(accS[kvt][qt][1] - mnew);
        const float p2 = fexp2(accS[kvt][qt][2] - mnew);
        const float p3 = fexp2(accS[kvt][qt][3] - mnew);
        ts += (p0 + p1) + (p2 + p3);
        pk01[qt][kvt] = pkbf(p0, p1);
        pk23[qt][kvt] = pkbf(p2, p3);
      }
      ts += __shfl_xor(ts, 16);
      ts += __shfl_xor(ts, 32);
      lst[qt] = lst[qt] * alpha[qt] + ts;
    }

#pragma unroll
    for (int dt = 0; dt < 4; dt++)
#pragma unroll
      for (int qt = 0; qt < 2; qt++)
#pragma unroll
        for (int r = 0; r < 4; r++)
          accO[dt][qt][r] *= alpha[qt];

    // PV in two kv-half passes through per-wave lP
#pragma unroll
    for (int kvh = 0; kvh < 2; kvh++) {
#pragma unroll
      for (int qt = 0; qt < 2; qt++) {
        const int prow = (qt * 16 + l15) * 64;
#pragma unroll
        for (int kt = 0; kt < 4; kt++) {
          const int kvt = kvh * 4 + kt;
          const int slot = (kt * 2 + (quad >> 1)) ^ e7;
          u32x2 pk; pk.x = pk01[qt][kvt]; pk.y = pk23[qt][kvt];
          *(u32x2*)&myP[prow + slot * 8 + (quad & 1) * 4] = pk;
        }
      }
      asm volatile("s_waitcnt lgkmcnt(0)" ::: "memory");
#pragma unroll
      for (int kk = 0; kk < 2; kk++) {
        const int kvc = kvh * 2 + kk;
        short8 pf[2];
#pragma unroll
        for (int qt = 0; qt < 2; qt++)
          pf[qt] = *(const short8*)&myP[(qt * 16 + l15) * 64 + (((kk * 4 + quad) ^ e7) << 3)];
#pragma unroll
        for (int dt = 0; dt < 4; dt++) {
          const short8 vf = *(const short8*)&cV[(dt * 16 + l15) * 128 + (((kvc * 4 + quad) ^ l15) << 3)];
#pragma unroll
          for (int qt = 0; qt < 2; qt++)
            accO[dt][qt] = __builtin_amdgcn_mfma_f32_16x16x32_bf16(vf, pf[qt], accO[dt][qt], 0, 0, 0);
        }
      }
    }
  }

  if (ns == 1) {
#pragma unroll
    for (int qt = 0; qt < 2; qt++) {
      const float inv = 1.0f / lst[qt];
      const int q = qblk + qt * 16 + l15;
#pragma unroll
      for (int dt = 0; dt < 4; dt++) {
        u32x2 o;
        o.x = pkbf(accO[dt][qt][0] * inv, accO[dt][qt][1] * inv);
        o.y = pkbf(accO[dt][qt][2] * inv, accO[dt][qt][3] * inv);
        *(u32x2*)&Out[((size_t)b * 2048 + q) * 1024 + h * 64 + dt * 16 + quad * 4] = o;
      }
    }
  } else {
    const int slot = bh * 72 + u;
    u16* op = Opart + (size_t)slot * 8192;
#pragma unroll
    for (int qt = 0; qt < 2; qt++) {
      const int ql = w * 32 + qt * 16 + l15;
#pragma unroll
      for (int dt = 0; dt < 4; dt++) {
        u32x2 o;
        o.x = pkbf(accO[dt][qt][0], accO[dt][qt][1]);
        o.y = pkbf(accO[dt][qt][2], accO[dt][qt][3]);
        *(u32x2*)&op[(size_t)ql * 64 + dt * 16 + quad * 4] = o;
      }
      if (quad == 0) {
        f2 v2; v2.x = mst[qt]; v2.y = lst[qt];
        ml[slot * 128 + ql] = v2;
      }
    }
  }
}

// ---------------- split-kv reduction (exp2 domain) ----------------
__global__ __launch_bounds__(256) void attn_reduce(const u16* __restrict__ Opart,
                                                   const f2* __restrict__ ml,
                                                   u16* __restrict__ Out) {
  const int qi = blockIdx.x + 2;
  const int bh = blockIdx.y;
  const int b = bh >> 4, h = bh & 15;
  const int p = qi >> 1;
  const int base = bh * 72 + p * (p + 1) + (qi & 1) * (p + 1);
  const int ns = (qi + 2) >> 1;
  const int t = threadIdx.x;
  const int q = t >> 1, dh = (t & 1) * 32;

  float m[8], l[8], wgt[8];
  float mmax = -3.0e38f;
  for (int s = 0; s < ns; s++) {
    f2 v = ml[(base + s) * 128 + q];
    m[s] = v.x; l[s] = v.y;
    mmax = fmaxf(mmax, m[s]);
  }
  float lsum = 0.0f;
  for (int s = 0; s < ns; s++) {
    wgt[s] = fexp2(m[s] - mmax);
    lsum += wgt[s] * l[s];
  }
  float acc[32] = {};
  for (int s = 0; s < ns; s++) {
    const u16* src = Opart + ((size_t)(base + s) * 128 + q) * 64 + dh;
    const float ws = wgt[s];
#pragma unroll
    for (int i = 0; i < 8; i++) {
      us4 vv = *(const us4*)&src[i * 4];
      acc[i * 4 + 0] += ws * bf2f(vv.x);
      acc[i * 4 + 1] += ws * bf2f(vv.y);
      acc[i * 4 + 2] += ws * bf2f(vv.z);
      acc[i * 4 + 3] += ws * bf2f(vv.w);
    }
  }
  const float inv = 1.0f / lsum;
  u16* dst = Out + ((size_t)b * 2048 + qi * 128 + q) * 1024 + h * 64 + dh;
#pragma unroll
  for (int i = 0; i < 8; i++) {
    u32x2 o;
    o.x = pkbf(acc[i * 4 + 0] * inv, acc[i * 4 + 1] * inv);
    o.y = pkbf(acc[i * 4 + 2] * inv, acc[i * 4 + 3] * inv);
    *(u32x2*)&dst[i * 4] = o;
  }
}

// ---------------- launcher ----------------
extern "C" void kernel_launch(void* const* d_in, const int* in_sizes, int n_in,
                              void* d_out, int out_size, void* d_ws, size_t ws_size,
                              hipStream_t stream) {
  (void)in_sizes; (void)n_in; (void)out_size; (void)ws_size;
  const float* hidden = (const float*)d_in[0];
  const float* attn_w = (const float*)d_in[1];
  const float* attn_b = (const float*)d_in[2];
  const float* proj_w = (const float*)d_in[3];
  const float* proj_b = (const float*)d_in[4];
  ConvW cw;
  for (int i = 0; i < 9; i++) {
    cw.w[i] = (const float*)d_in[5 + 2 * i];
    cw.b[i] = (const float*)d_in[6 + 2 * i];
  }

  uint8_t* ws = (uint8_t*)d_ws;
  u16* h_bf   = (u16*)(ws + 0);          //  8,388,608 B
  u16* wqkvT  = (u16*)(ws + 8388608);    //  6,291,456 B
  u16* qkvpre = (u16*)(ws + 14680064);   // 25,165,824 B  [3][2][16][2048][64]
  u16* qpost  = (u16*)(ws + 39845888);   //  8,388,608 B  [2][16][2048][64]
  u16* kpost  = (u16*)(ws + 48234496);   //  8,388,608 B
  u16* vpostT = (u16*)(ws + 56623104);   //  8,388,608 B  [2][16][64][2048]
  u16* attno  = (u16*)(ws + 65011712);   //  8,388,608 B  [2][2048][1024]
  u16* wprojT = (u16*)(ws + 73400320);   //  2,097,152 B
  f2*  ml     = (f2*) (ws + 75497472);   //  2,359,296 B  [2304][128] (m,l)
  u16* Opart  = (u16*)(ws + 0);          // 37,748,736 B  overlay on prologue bufs

  prep_fused<<<8192, 256, 0, stream>>>(hidden, h_bf, attn_w, wqkvT, proj_w, wprojT);
  gemm_bt<0, 128, 6><<<768, 256, 0, stream>>>(h_bf, wqkvT, attn_b, (void*)qkvpre, 4096, 3072, 1024);
  conv_mix<<<dim3(16, 16, 6), 256, 0, stream>>>(qkvpre, cw, qpost, kpost, vpostT);
  attn_fwd<<<dim3(2304), 256, 0, stream>>>(qpost, kpost, vpostT, attno, Opart, ml);
  attn_reduce<<<dim3(14, 32), 256, 0, stream>>>(Opart, ml, attno);
  gemm_bt<1, 64, 8><<<512, 256, 0, stream>>>(attno, wprojT, proj_b, d_out, 4096, 1024, 1024);
}